// Round 14
// baseline (166.303 us; speedup 1.0000x reference)
//
#include <hip/hip_runtime.h>
#include <cstdint>
#include <cstddef>

// Problem constants: B=2, T=2048, C=1024, H=16, D=64
#define SEQ_T 2048
#define NHEAD 16

typedef __attribute__((ext_vector_type(8))) short short8;
typedef __attribute__((ext_vector_type(4))) float f32x4;
typedef __attribute__((ext_vector_type(16))) float f32x16;

__device__ __forceinline__ unsigned short f2bf(float f) {
  union { float f; unsigned int u; } v; v.f = f;
  return (unsigned short)((v.u + 0x7FFFu + ((v.u >> 16) & 1u)) >> 16);
}
__device__ __forceinline__ float bf2f(unsigned short u) {
  union { unsigned int u; float f; } v; v.u = ((unsigned int)u) << 16;
  return v.f;
}

__device__ __forceinline__ unsigned cvtpk(float lo, float hi) {
  unsigned r;
  asm("v_cvt_pk_bf16_f32 %0, %1, %2" : "=v"(r) : "v"(lo), "v"(hi));
  return r;
}

__device__ __forceinline__ float max3f(float a, float b, float c) {
  float r;
  asm("v_max3_f32 %0, %1, %2, %3" : "=v"(r) : "v"(a), "v"(b), "v"(c));
  return r;
}

// permlane32_swap via builtin (compiler inserts the required hazard waits)
#if __has_builtin(__builtin_amdgcn_permlane32_swap)
__device__ __forceinline__ void plswap(unsigned& a, unsigned& b) {
  auto r = __builtin_amdgcn_permlane32_swap(a, b, false, false);
  a = r[0];
  b = r[1];
}
#else
__device__ __forceinline__ void plswap(unsigned& a, unsigned& b) {
  asm volatile("s_nop 1\n\tv_permlane32_swap_b32 %0, %1\n\ts_nop 1"
               : "+v"(a), "+v"(b));
}
#endif

__device__ __forceinline__ float xhalf_max(float x) {
  unsigned a = __builtin_bit_cast(unsigned, x), b = a;
  plswap(a, b);
  return fmaxf(__builtin_bit_cast(float, a), __builtin_bit_cast(float, b));
}
__device__ __forceinline__ float xhalf_add(float x) {
  unsigned a = __builtin_bit_cast(unsigned, x), b = a;
  plswap(a, b);
  return __builtin_bit_cast(float, a) + __builtin_bit_cast(float, b);
}

// max of 16 via v_max3 tree (T17)
__device__ __forceinline__ float vmax16(const f32x16 v) {
  float m0 = max3f(v[0], v[1], v[2]);
  float m1 = max3f(v[3], v[4], v[5]);
  float m2 = max3f(v[6], v[7], v[8]);
  float m3 = max3f(v[9], v[10], v[11]);
  float m4 = max3f(v[12], v[13], v[14]);
  float m5 = max3f(m0, m1, v[15]);
  float m6 = max3f(m2, m3, m4);
  return fmaxf(m5, m6);
}

__device__ __forceinline__ void gl_lds16(const void* g, void* l) {
  __builtin_amdgcn_global_load_lds(
      (__attribute__((address_space(1))) void*)(void*)g,
      (__attribute__((address_space(3))) void*)l, 16, 0, 0);
}

// ---------- fused prep: fp32->bf16 cvt, 2x transpose-convert, RoPE table ----------
__global__ void k_prep(const float* __restrict__ x,
                       const float* __restrict__ Wa,
                       const float* __restrict__ Wp,
                       unsigned short* __restrict__ xb,
                       unsigned short* __restrict__ wat,
                       unsigned short* __restrict__ wpt,
                       float2* __restrict__ tab) {
  const int b = blockIdx.x, tid = threadIdx.x;
  if (b < 4096) {                       // x cvt: 1M threads x float4
    int i = b * 256 + tid;
    float4 v = ((const float4*)x)[i];
    unsigned long long pk = (unsigned long long)f2bf(v.x)
                          | ((unsigned long long)f2bf(v.y) << 16)
                          | ((unsigned long long)f2bf(v.z) << 32)
                          | ((unsigned long long)f2bf(v.w) << 48);
    ((unsigned long long*)xb)[i] = pk;
  } else if (b < 5632) {                // W_attn [1024,3072] -> [3072,1024]
    int idx = (b - 4096) * 256 + tid;
    int n = idx % 3072, k0 = (idx / 3072) * 8;
    short8 v;
#pragma unroll
    for (int j = 0; j < 8; ++j)
      v[j] = (short)f2bf(Wa[(size_t)(k0 + j) * 3072 + n]);
    *(short8*)&wat[(size_t)n * 1024 + k0] = v;
  } else if (b < 6144) {                // W_proj [1024,1024] -> transpose
    int idx = (b - 5632) * 256 + tid;
    int n = idx & 1023, k0 = (idx >> 10) * 8;
    short8 v;
#pragma unroll
    for (int j = 0; j < 8; ++j)
      v[j] = (short)f2bf(Wp[(size_t)(k0 + j) * 1024 + n]);
    *(short8*)&wpt[(size_t)n * 1024 + k0] = v;
  } else {                              // RoPE table [2048][32]
    int idx = (b - 6144) * 256 + tid;
    int t = idx >> 5, i = idx & 31;
    float inv = powf(10000.0f, -(float)(2 * i) / 64.0f);
    float f = (float)t * inv;
    tab[idx] = make_float2(cosf(f), sinf(f));
  }
}

// ---------- GEMM1: qkv = x @ W_attn^T(+b), fused RoPE; q/k -> [B,H,T,D], v -> V^T [B,H,D,T] ----------
__global__ void k_gemm_qkv(const unsigned short* __restrict__ A,
                           const unsigned short* __restrict__ Bt,
                           const float* __restrict__ bias,
                           const float2* __restrict__ cs,
                           unsigned short* __restrict__ qo,
                           unsigned short* __restrict__ ko,
                           unsigned short* __restrict__ vo) {
  __shared__ unsigned short lA[128 * 32];
  __shared__ unsigned short lB[128 * 32];
  const int K = 1024;
  const int bn = blockIdx.x, bm = blockIdx.y;
  const int tid = threadIdx.x, w = tid >> 6, l = tid & 63;
  const int lr = l & 15, lh = l >> 4;
  const int wm = w >> 1, wn = w & 1;

  f32x4 acc[4][4];
#pragma unroll
  for (int m = 0; m < 4; ++m)
#pragma unroll
    for (int n = 0; n < 4; ++n)
#pragma unroll
      for (int i = 0; i < 4; ++i) acc[m][n][i] = 0.f;

  const unsigned short* ga0 = A + (size_t)(bm * 128 + w * 16 + (l >> 2)) * K + (l & 3) * 8;
  const unsigned short* gb0 = Bt + (size_t)(bn * 128 + w * 16 + (l >> 2)) * K + (l & 3) * 8;
  unsigned short* la0 = &lA[w * 512];
  unsigned short* la1 = &lA[(w + 4) * 512];
  unsigned short* lb0 = &lB[w * 512];
  unsigned short* lb1 = &lB[(w + 4) * 512];

  for (int kt = 0; kt < K; kt += 32) {
    gl_lds16(ga0 + kt, la0);
    gl_lds16(ga0 + (size_t)64 * K + kt, la1);
    gl_lds16(gb0 + kt, lb0);
    gl_lds16(gb0 + (size_t)64 * K + kt, lb1);
    __syncthreads();
    short8 af[4], bf[4];
#pragma unroll
    for (int m = 0; m < 4; ++m) af[m] = *(const short8*)&lA[(wm * 64 + m * 16 + lr) * 32 + lh * 8];
#pragma unroll
    for (int n = 0; n < 4; ++n) bf[n] = *(const short8*)&lB[(wn * 64 + n * 16 + lr) * 32 + lh * 8];
#pragma unroll
    for (int m = 0; m < 4; ++m)
#pragma unroll
      for (int n = 0; n < 4; ++n)
        acc[m][n] = __builtin_amdgcn_mfma_f32_16x16x32_bf16(af[m], bf[n], acc[m][n], 0, 0, 0);
    __syncthreads();
  }

  const int col0 = bn * 128 + wn * 64;
  const int row0 = bm * 128 + wm * 64;
  const int sec = col0 >> 10;
  const int hh = (col0 >> 6) & 15;
  float bl[4];
#pragma unroll
  for (int n = 0; n < 4; ++n) bl[n] = bias[col0 + n * 16 + lr];

  if (sec == 2) {
    const int b = row0 >> 11;
    unsigned short* vtp = vo + (size_t)(b * 16 + hh) * 64 * 2048;
#pragma unroll
    for (int n = 0; n < 4; ++n) {
      int d = n * 16 + lr;
#pragma unroll
      for (int m = 0; m < 4; ++m) {
        int t = (row0 + m * 16 + lh * 4) & 2047;
        unsigned long long pk = (unsigned long long)f2bf(acc[m][n][0] + bl[n])
                              | ((unsigned long long)f2bf(acc[m][n][1] + bl[n]) << 16)
                              | ((unsigned long long)f2bf(acc[m][n][2] + bl[n]) << 32)
                              | ((unsigned long long)f2bf(acc[m][n][3] + bl[n]) << 48);
        *(unsigned long long*)&vtp[(size_t)d * 2048 + t] = pk;
      }
    }
  } else {
    unsigned short* dst = (sec == 0) ? qo : ko;
#pragma unroll
    for (int m = 0; m < 4; ++m)
#pragma unroll
      for (int i = 0; i < 4; ++i) {
        int row = row0 + m * 16 + lh * 4 + i;
        int t = row & 2047, b = row >> 11;
        size_t ob = ((size_t)(b * 16 + hh) * 2048 + t) * 64;
#pragma unroll
        for (int n = 0; n < 4; ++n) {
          float v = acc[m][n][i] + bl[n];
          float pv = acc[m][n ^ 2][i] + bl[n ^ 2];
          int d = n * 16 + lr;
          float2 c = cs[t * 32 + (d & 31)];
          float rot = (d < 32) ? -pv : pv;
          dst[ob + d] = f2bf(v * c.x + rot * c.y);
        }
      }
  }
}

// ---------- flash attention: kv-split grid 1024, DIRECT L2->reg K/V (no LDS staging) ----------
// Per-XCD K/V = 2MB (L2-fits); the 4 wq-waves of a CU read the same K/V half-tiles -> L1
// serves the reuse. Loop is barrier-free; waves fully independent. LDS only for epilogue merge.
__global__ __launch_bounds__(512, 4) void k_attn(const unsigned short* __restrict__ Q,
                       const unsigned short* __restrict__ Kg,
                       const unsigned short* __restrict__ VT,
                       unsigned short* __restrict__ P0,
                       unsigned short* __restrict__ P1,
                       float2* __restrict__ ML) {
  __shared__ unsigned short smem[16896];   // epilogue merge scratch only (33KB)
  const int id = blockIdx.x;
  const int xcd = id & 7, u = id >> 3;
  const int a = u & 31, sweep = u >> 5;
  const int g = a & 3, j = a >> 2;
  const int bh = xcd * 4 + g;
  const int qt = (sweep & 1) ? (15 - j) : j;
  const int sp = sweep >> 1;
  const int tid = threadIdx.x, w = tid >> 6, l = tid & 63;
  const int wq = w & 3, wk = w >> 2;
  const int lq = l & 31, hi = l >> 5;
  const size_t base = (size_t)bh * SEQ_T * 64;
  const float CE = 0.18033688f;   // 0.125 * log2(e)
  const float DTHR = 44.3614f;    // 8 / CE

  const int qrow = qt * 128 + wq * 32 + lq;
  short8 qf[4];
#pragma unroll
  for (int c = 0; c < 4; ++c)
    qf[c] = *(const short8*)&Q[base + (size_t)qrow * 64 + c * 16 + hi * 8];

  // direct-read bases: K row (kv) fixed per lane; V rows (d) fixed per lane
  const unsigned short* kp0 = Kg + base + (size_t)(wk * 32 + lq) * 64 + hi * 8;
  const unsigned short* vp0 = VT + base + (size_t)lq * 2048 + (wk * 4 + hi) * 8;

  float mi = -1.0e30f, li = 0.f;           // li is PER-HALF until epilogue
  f32x16 oc0, oc1;
#pragma unroll
  for (int r = 0; r < 16; ++r) { oc0[r] = 0.f; oc1[r] = 0.f; }

  const int nit = qt + 1;
  const int kt0 = sp * nit;
  const int mfrom = 2 * qt;

  for (int it = 0; it < nit; ++it) {
    const int kt = kt0 + it;

    // S^T = K Q^T over this wave's 32-kv half (K direct from L1/L2)
    const unsigned short* kp = kp0 + (size_t)kt * 4096;
    f32x16 st;
#pragma unroll
    for (int r = 0; r < 16; ++r) st[r] = 0.f;
    __builtin_amdgcn_s_setprio(1);
#pragma unroll
    for (int c = 0; c < 4; ++c) {
      const short8 kf = *(const short8*)&kp[c * 16];
      st = __builtin_amdgcn_mfma_f32_32x32x16_bf16(kf, qf[c], st, 0, 0, 0);
    }
    __builtin_amdgcn_s_setprio(0);

    if (kt >= mfrom) {                      // causal mask (unscaled scores)
#pragma unroll
      for (int r = 0; r < 16; ++r) {
        int kvg = kt * 64 + wk * 32 + (r & 3) + 8 * (r >> 2) + 4 * hi;
        if (kvg > qrow) st[r] = -3.0e38f;
      }
    }

    // online softmax (in-register; cross-half max via permlane)
    float tm = xhalf_max(vmax16(st));
    if (!__all(tm <= mi + DTHR)) {          // T13 defer-rescale
      float mn = fmaxf(mi, tm);
      float scq = exp2f((mi - mn) * CE);
      mi = mn;
      li *= scq;
#pragma unroll
      for (int r = 0; r < 16; ++r) {
        float sc_r = __shfl(scq, (r & 3) + 8 * (r >> 2) + 4 * hi, 64);
        oc0[r] *= sc_r;
        oc1[r] *= sc_r;
      }
    }
    const float nb = mi * CE;
    float rs = 0.f;
#pragma unroll
    for (int r = 0; r < 16; ++r) {
      float p = exp2f(fmaf(st[r], CE, -nb));
      st[r] = p;
      rs += p;
    }
    li += rs;                               // per-half; combined at epilogue

    // pack P into PV A-fragments
    short8 pa[2];
#pragma unroll
    for (int kc = 0; kc < 2; ++kc) {
      const int o = kc * 8;
      unsigned w0 = cvtpk(st[o + 0], st[o + 1]);
      unsigned w1 = cvtpk(st[o + 2], st[o + 3]);
      unsigned w2 = cvtpk(st[o + 4], st[o + 5]);
      unsigned w3 = cvtpk(st[o + 6], st[o + 7]);
      plswap(w0, w2);
      plswap(w1, w3);
      uint4 F;
      F.x = w0; F.y = w1; F.z = w2; F.w = w3;
      pa[kc] = __builtin_bit_cast(short8, F);
    }

    // O += P V over this wave's 32-kv half (V direct from L1/L2)
    {
      const unsigned short* vp = vp0 + (size_t)kt * 64;
      short8 vbf[2][2];
#pragma unroll
      for (int dt = 0; dt < 2; ++dt)
#pragma unroll
        for (int kc = 0; kc < 2; ++kc)
          vbf[dt][kc] = *(const short8*)&vp[(size_t)dt * 32 * 2048 + kc * 16];
      __builtin_amdgcn_s_setprio(1);
#pragma unroll
      for (int kc = 0; kc < 2; ++kc) {
        oc0 = __builtin_amdgcn_mfma_f32_32x32x16_bf16(pa[kc], vbf[0][kc], oc0, 0, 0, 0);
        oc1 = __builtin_amdgcn_mfma_f32_32x32x16_bf16(pa[kc], vbf[1][kc], oc1, 0, 0, 0);
      }
      __builtin_amdgcn_s_setprio(0);
    }
  }

  li = xhalf_add(li);                       // combine the two lane-half partial sums

  // ---- epilogue: merge wk halves, write NORMALIZED bf16 partial + (m, l) ----
  __syncthreads();
  float* obuf = (float*)smem;               // [wq][32 q][64 d] fp32 = 32 KB
  float* mlb  = (float*)&smem[16384];       // [wq][32 q][2] (m, l) = 1 KB
  if (wk == 1) {
#pragma unroll
    for (int r = 0; r < 16; ++r) {
      const int q = (r & 3) + 8 * (r >> 2) + 4 * hi;
      obuf[wq * 2048 + q * 64 + lq]      = oc0[r];
      obuf[wq * 2048 + q * 64 + 32 + lq] = oc1[r];
    }
    if (hi == 0) {
      mlb[wq * 64 + lq * 2 + 0] = mi;
      mlb[wq * 64 + lq * 2 + 1] = li;
    }
  }
  __syncthreads();
  if (wk == 0) {
    unsigned short* dst = sp ? P1 : P0;
    const int hh = bh & 15, bb = bh >> 4;
#pragma unroll
    for (int r = 0; r < 16; ++r) {
      const int q = (r & 3) + 8 * (r >> 2) + 4 * hi;
      float m0 = __shfl(mi, q, 64), l0 = __shfl(li, q, 64);
      float m1 = mlb[wq * 64 + q * 2 + 0], l1 = mlb[wq * 64 + q * 2 + 1];
      float mm = fmaxf(m0, m1);
      float f0 = exp2f((m0 - mm) * CE), f1 = exp2f((m1 - mm) * CE);
      float dn = f0 * l0 + f1 * l1;
      float inv = (dn > 0.f) ? (1.0f / dn) : 0.f;
      float o0 = (f0 * oc0[r] + f1 * obuf[wq * 2048 + q * 64 + lq]) * inv;
      float o1 = (f0 * oc1[r] + f1 * obuf[wq * 2048 + q * 64 + 32 + lq]) * inv;
      int qg = qt * 128 + wq * 32 + q;
      size_t ob = (size_t)(bb * 2048 + qg) * 1024 + hh * 64;
      dst[ob + lq]      = f2bf(o0);
      dst[ob + 32 + lq] = f2bf(o1);
      if (lq == 0) ML[(size_t)(sp * 32 + bh) * 2048 + qg] = make_float2(mm, dn);
    }
  }
}

// ---------- combine the two kv-splits: O = (w0*O0 + w1*O1), in place on P0 ----------
__global__ void k_combine(const unsigned short* __restrict__ P1,
                          const float2* __restrict__ ML,
                          unsigned short* __restrict__ P0) {
  const float CE = 0.18033688f;
  int idx = blockIdx.x * 256 + threadIdx.x;
  int flat = idx * 8;
  int c = flat & 1023, t = (flat >> 10) & 2047, b = flat >> 21;
  int bh = b * 16 + (c >> 6);
  float2 a0 = ML[(size_t)bh * 2048 + t];
  float2 a1 = ML[(size_t)(32 + bh) * 2048 + t];
  float mm = fmaxf(a0.x, a1.x);
  float w0 = exp2f((a0.x - mm) * CE) * a0.y;
  float w1 = exp2f((a1.x - mm) * CE) * a1.y;
  float inv = 1.0f / (w0 + w1);
  w0 *= inv; w1 *= inv;
  short8 o0 = *(const short8*)&P0[flat];
  short8 o1 = *(const short8*)&P1[flat];
  short8 o;
#pragma unroll
  for (int k = 0; k < 8; ++k)
    o[k] = (short)f2bf(w0 * bf2f((unsigned short)o0[k]) + w1 * bf2f((unsigned short)o1[k]));
  *(short8*)&P0[flat] = o;
}

// ---------- GEMM2: out = attn_out @ W_proj^T + b (fp32 out) ----------
// 64x128 tile, grid (8 bn, 64 bm) = 512 blocks = 2/CU (R11-proven).
__global__ void k_gemm_proj(const unsigned short* __restrict__ A,
                            const unsigned short* __restrict__ Bt,
                            const float* __restrict__ bias,
                            float* __restrict__ out) {
  __shared__ unsigned short lA[64 * 32];
  __shared__ unsigned short lB[128 * 32];
  const int K = 1024;
  const int bn = blockIdx.x, bm = blockIdx.y;
  const int tid = threadIdx.x, w = tid >> 6, l = tid & 63;
  const int lr = l & 15, lh = l >> 4;
  const int wm = w >> 1, wn = w & 1;      // 2x2 waves over 64 rows x 128 cols

  f32x4 acc[2][4];
#pragma unroll
  for (int m = 0; m < 2; ++m)
#pragma unroll
    for (int n = 0; n < 4; ++n)
#pragma unroll
      for (int i = 0; i < 4; ++i) acc[m][n][i] = 0.f;

  const unsigned short* ga0 = A + (size_t)(bm * 64 + (tid >> 2)) * K + (tid & 3) * 8;
  const unsigned short* gb0 = Bt + (size_t)(bn * 128 + w * 16 + (l >> 2)) * K + (l & 3) * 8;
  unsigned short* la0 = &lA[w * 512];
  unsigned short* lb0 = &lB[w * 512];
  unsigned short* lb1 = &lB[(w + 4) * 512];

  for (int kt = 0; kt < K; kt += 32) {
    gl_lds16(ga0 + kt, la0);
    gl_lds16(gb0 + kt, lb0);
    gl_lds16(gb0 + (size_t)64 * K + kt, lb1);
    __syncthreads();
    short8 af[2], bf[4];
#pragma unroll
    for (int m = 0; m < 2; ++m) af[m] = *(const short8*)&lA[(wm * 32 + m * 16 + lr) * 32 + lh * 8];
#pragma unroll
    for (int n = 0; n < 4; ++n) bf[n] = *(const short8*)&lB[(wn * 64 + n * 16 + lr) * 32 + lh * 8];
#pragma unroll
    for (int m = 0; m < 2; ++m)
#pragma unroll
      for (int n = 0; n < 4; ++n)
        acc[m][n] = __builtin_amdgcn_mfma_f32_16x16x32_bf16(af[m], bf[n], acc[m][n], 0, 0, 0);
    __syncthreads();
  }

  const int col0 = bn * 128 + wn * 64;
  const int row0 = bm * 64 + wm * 32;
  float bl[4];
#pragma unroll
  for (int n = 0; n < 4; ++n) bl[n] = bias[col0 + n * 16 + lr];
#pragma unroll
  for (int m = 0; m < 2; ++m)
#pragma unroll
    for (int i = 0; i < 4; ++i) {
      int row = row0 + m * 16 + lh * 4 + i;
#pragma unroll
      for (int n = 0; n < 4; ++n)
        out[(size_t)row * 1024 + col0 + n * 16 + lr] = acc[m][n][i] + bl[n];
    }
}

extern "C" void kernel_launch(void* const* d_in, const int* in_sizes, int n_in,
                              void* d_out, int out_size, void* d_ws, size_t ws_size,
                              hipStream_t stream) {
  const float* x     = (const float*)d_in[0];
  const float* Wattn = (const float*)d_in[1];
  const float* battn = (const float*)d_in[2];
  const float* Wproj = (const float*)d_in[3];
  const float* bproj = (const float*)d_in[4];
  float* out = (float*)d_out;

  char* ws = (char*)d_ws;
  unsigned short* xb  = (unsigned short*)(ws);                  // 8 MB  x bf16 -> sp1 partial
  unsigned short* wat = (unsigned short*)(ws + (8ull  << 20));  // 6 MB  W_attn^T -> ML (1MB)
  unsigned short* wpt = (unsigned short*)(ws + (14ull << 20));  // 2 MB
  unsigned short* qa  = (unsigned short*)(ws + (16ull << 20));  // 8 MB
  unsigned short* ka  = (unsigned short*)(ws + (24ull << 20));  // 8 MB
  unsigned short* va  = (unsigned short*)(ws + (32ull << 20));  // 8 MB  V^T [BH][D][T]
  unsigned short* ob  = (unsigned short*)(ws + (40ull << 20));  // 8 MB  sp0 partial / attn out
  float2* cs          = (float2*)(ws + (48ull << 20));          // 512 KB
  float2* ml          = (float2*)wat;                           // 1 MB (wat dead after GEMM1)

  k_prep<<<6400, 256, 0, stream>>>(x, Wattn, Wproj, xb, wat, wpt, cs);
  k_gemm_qkv<<<dim3(24, 32), 256, 0, stream>>>(xb, wat, battn, cs, qa, ka, va);
  k_attn<<<1024, 512, 0, stream>>>(qa, ka, va, ob, xb, ml);
  k_combine<<<2048, 256, 0, stream>>>(xb, ml, ob);
  k_gemm_proj<<<dim3(8, 64), 256, 0, stream>>>(ob, wpt, bproj, out);
}

// Round 15
// 124.936 us; speedup vs baseline: 1.3311x; 1.3311x over previous
//
#include <hip/hip_runtime.h>
#include <cstdint>
#include <cstddef>

// Problem constants: B=2, T=2048, C=1024, H=16, D=64
#define SEQ_T 2048
#define NHEAD 16

typedef __attribute__((ext_vector_type(8))) short short8;
typedef __attribute__((ext_vector_type(4))) float f32x4;
typedef __attribute__((ext_vector_type(16))) float f32x16;

__device__ __forceinline__ unsigned short f2bf(float f) {
  union { float f; unsigned int u; } v; v.f = f;
  return (unsigned short)((v.u + 0x7FFFu + ((v.u >> 16) & 1u)) >> 16);
}
__device__ __forceinline__ float bf2f(unsigned short u) {
  union { unsigned int u; float f; } v; v.u = ((unsigned int)u) << 16;
  return v.f;
}

__device__ __forceinline__ unsigned cvtpk(float lo, float hi) {
  unsigned r;
  asm("v_cvt_pk_bf16_f32 %0, %1, %2" : "=v"(r) : "v"(lo), "v"(hi));
  return r;
}

__device__ __forceinline__ float max3f(float a, float b, float c) {
  float r;
  asm("v_max3_f32 %0, %1, %2, %3" : "=v"(r) : "v"(a), "v"(b), "v"(c));
  return r;
}

// permlane32_swap via builtin (compiler inserts the required hazard waits)
#if __has_builtin(__builtin_amdgcn_permlane32_swap)
__device__ __forceinline__ void plswap(unsigned& a, unsigned& b) {
  auto r = __builtin_amdgcn_permlane32_swap(a, b, false, false);
  a = r[0];
  b = r[1];
}
#else
__device__ __forceinline__ void plswap(unsigned& a, unsigned& b) {
  asm volatile("s_nop 1\n\tv_permlane32_swap_b32 %0, %1\n\ts_nop 1"
               : "+v"(a), "+v"(b));
}
#endif

__device__ __forceinline__ float xhalf_max(float x) {
  unsigned a = __builtin_bit_cast(unsigned, x), b = a;
  plswap(a, b);
  return fmaxf(__builtin_bit_cast(float, a), __builtin_bit_cast(float, b));
}
__device__ __forceinline__ float xhalf_add(float x) {
  unsigned a = __builtin_bit_cast(unsigned, x), b = a;
  plswap(a, b);
  return __builtin_bit_cast(float, a) + __builtin_bit_cast(float, b);
}

// max of 16 via v_max3 tree (T17)
__device__ __forceinline__ float vmax16(const f32x16 v) {
  float m0 = max3f(v[0], v[1], v[2]);
  float m1 = max3f(v[3], v[4], v[5]);
  float m2 = max3f(v[6], v[7], v[8]);
  float m3 = max3f(v[9], v[10], v[11]);
  float m4 = max3f(v[12], v[13], v[14]);
  float m5 = max3f(m0, m1, v[15]);
  float m6 = max3f(m2, m3, m4);
  return fmaxf(m5, m6);
}

__device__ __forceinline__ void gl_lds16(const void* g, void* l) {
  __builtin_amdgcn_global_load_lds(
      (__attribute__((address_space(1))) void*)(void*)g,
      (__attribute__((address_space(3))) void*)l, 16, 0, 0);
}

// ---------- fused prep: fp32->bf16 cvt, 2x transpose-convert, RoPE table ----------
__global__ void k_prep(const float* __restrict__ x,
                       const float* __restrict__ Wa,
                       const float* __restrict__ Wp,
                       unsigned short* __restrict__ xb,
                       unsigned short* __restrict__ wat,
                       unsigned short* __restrict__ wpt,
                       float2* __restrict__ tab) {
  const int b = blockIdx.x, tid = threadIdx.x;
  if (b < 4096) {                       // x cvt: 1M threads x float4
    int i = b * 256 + tid;
    float4 v = ((const float4*)x)[i];
    unsigned long long pk = (unsigned long long)f2bf(v.x)
                          | ((unsigned long long)f2bf(v.y) << 16)
                          | ((unsigned long long)f2bf(v.z) << 32)
                          | ((unsigned long long)f2bf(v.w) << 48);
    ((unsigned long long*)xb)[i] = pk;
  } else if (b < 5632) {                // W_attn [1024,3072] -> [3072,1024]
    int idx = (b - 4096) * 256 + tid;
    int n = idx % 3072, k0 = (idx / 3072) * 8;
    short8 v;
#pragma unroll
    for (int j = 0; j < 8; ++j)
      v[j] = (short)f2bf(Wa[(size_t)(k0 + j) * 3072 + n]);
    *(short8*)&wat[(size_t)n * 1024 + k0] = v;
  } else if (b < 6144) {                // W_proj [1024,1024] -> transpose
    int idx = (b - 5632) * 256 + tid;
    int n = idx & 1023, k0 = (idx >> 10) * 8;
    short8 v;
#pragma unroll
    for (int j = 0; j < 8; ++j)
      v[j] = (short)f2bf(Wp[(size_t)(k0 + j) * 1024 + n]);
    *(short8*)&wpt[(size_t)n * 1024 + k0] = v;
  } else {                              // RoPE table [2048][32]
    int idx = (b - 6144) * 256 + tid;
    int t = idx >> 5, i = idx & 31;
    float inv = powf(10000.0f, -(float)(2 * i) / 64.0f);
    float f = (float)t * inv;
    tab[idx] = make_float2(cosf(f), sinf(f));
  }
}

// ---------- GEMM1: qkv = x @ W_attn^T(+b), fused RoPE; q/k -> [B,H,T,D], v -> V^T [B,H,D,T] ----------
__global__ void k_gemm_qkv(const unsigned short* __restrict__ A,
                           const unsigned short* __restrict__ Bt,
                           const float* __restrict__ bias,
                           const float2* __restrict__ cs,
                           unsigned short* __restrict__ qo,
                           unsigned short* __restrict__ ko,
                           unsigned short* __restrict__ vo) {
  __shared__ unsigned short lA[128 * 32];
  __shared__ unsigned short lB[128 * 32];
  const int K = 1024;
  const int bn = blockIdx.x, bm = blockIdx.y;
  const int tid = threadIdx.x, w = tid >> 6, l = tid & 63;
  const int lr = l & 15, lh = l >> 4;
  const int wm = w >> 1, wn = w & 1;

  f32x4 acc[4][4];
#pragma unroll
  for (int m = 0; m < 4; ++m)
#pragma unroll
    for (int n = 0; n < 4; ++n)
#pragma unroll
      for (int i = 0; i < 4; ++i) acc[m][n][i] = 0.f;

  const unsigned short* ga0 = A + (size_t)(bm * 128 + w * 16 + (l >> 2)) * K + (l & 3) * 8;
  const unsigned short* gb0 = Bt + (size_t)(bn * 128 + w * 16 + (l >> 2)) * K + (l & 3) * 8;
  unsigned short* la0 = &lA[w * 512];
  unsigned short* la1 = &lA[(w + 4) * 512];
  unsigned short* lb0 = &lB[w * 512];
  unsigned short* lb1 = &lB[(w + 4) * 512];

  for (int kt = 0; kt < K; kt += 32) {
    gl_lds16(ga0 + kt, la0);
    gl_lds16(ga0 + (size_t)64 * K + kt, la1);
    gl_lds16(gb0 + kt, lb0);
    gl_lds16(gb0 + (size_t)64 * K + kt, lb1);
    __syncthreads();
    short8 af[4], bf[4];
#pragma unroll
    for (int m = 0; m < 4; ++m) af[m] = *(const short8*)&lA[(wm * 64 + m * 16 + lr) * 32 + lh * 8];
#pragma unroll
    for (int n = 0; n < 4; ++n) bf[n] = *(const short8*)&lB[(wn * 64 + n * 16 + lr) * 32 + lh * 8];
#pragma unroll
    for (int m = 0; m < 4; ++m)
#pragma unroll
      for (int n = 0; n < 4; ++n)
        acc[m][n] = __builtin_amdgcn_mfma_f32_16x16x32_bf16(af[m], bf[n], acc[m][n], 0, 0, 0);
    __syncthreads();
  }

  const int col0 = bn * 128 + wn * 64;
  const int row0 = bm * 128 + wm * 64;
  const int sec = col0 >> 10;
  const int hh = (col0 >> 6) & 15;
  float bl[4];
#pragma unroll
  for (int n = 0; n < 4; ++n) bl[n] = bias[col0 + n * 16 + lr];

  if (sec == 2) {
    const int b = row0 >> 11;
    unsigned short* vtp = vo + (size_t)(b * 16 + hh) * 64 * 2048;
#pragma unroll
    for (int n = 0; n < 4; ++n) {
      int d = n * 16 + lr;
#pragma unroll
      for (int m = 0; m < 4; ++m) {
        int t = (row0 + m * 16 + lh * 4) & 2047;
        unsigned long long pk = (unsigned long long)f2bf(acc[m][n][0] + bl[n])
                              | ((unsigned long long)f2bf(acc[m][n][1] + bl[n]) << 16)
                              | ((unsigned long long)f2bf(acc[m][n][2] + bl[n]) << 32)
                              | ((unsigned long long)f2bf(acc[m][n][3] + bl[n]) << 48);
        *(unsigned long long*)&vtp[(size_t)d * 2048 + t] = pk;
      }
    }
  } else {
    unsigned short* dst = (sec == 0) ? qo : ko;
#pragma unroll
    for (int m = 0; m < 4; ++m)
#pragma unroll
      for (int i = 0; i < 4; ++i) {
        int row = row0 + m * 16 + lh * 4 + i;
        int t = row & 2047, b = row >> 11;
        size_t ob = ((size_t)(b * 16 + hh) * 2048 + t) * 64;
#pragma unroll
        for (int n = 0; n < 4; ++n) {
          float v = acc[m][n][i] + bl[n];
          float pv = acc[m][n ^ 2][i] + bl[n ^ 2];
          int d = n * 16 + lr;
          float2 c = cs[t * 32 + (d & 31)];
          float rot = (d < 32) ? -pv : pv;
          dst[ob + d] = f2bf(v * c.x + rot * c.y);
        }
      }
  }
}

// ---------- flash attention: kv-split grid 1024, counted-vmcnt pipeline (T4) ----------
// 3-deep K buffers (K(it+2) staged one full iteration ahead) + 2-deep V buffers.
// End-of-iter wait is vmcnt(1) (K(it+2) stays in flight) instead of __syncthreads'
// vmcnt(0) drain -> K stage latency fully hidden under one iteration of compute.
// LDS 40KB (3K + 2V @ 8KB each) -> still 4 blocks/CU.
__global__ __launch_bounds__(512, 4) void k_attn(const unsigned short* __restrict__ Q,
                       const unsigned short* __restrict__ Kg,
                       const unsigned short* __restrict__ VT,
                       unsigned short* __restrict__ P0,
                       unsigned short* __restrict__ P1,
                       float2* __restrict__ ML) {
  __shared__ unsigned short smem[20480];   // 40KB: K0@0 K1@4096 K2@8192 V0@12288 V1@16384
  const int id = blockIdx.x;
  const int xcd = id & 7, u = id >> 3;
  const int a = u & 31, sweep = u >> 5;
  const int g = a & 3, j = a >> 2;
  const int bh = xcd * 4 + g;
  const int qt = (sweep & 1) ? (15 - j) : j;
  const int sp = sweep >> 1;
  const int tid = threadIdx.x, w = tid >> 6, l = tid & 63;
  const int wq = w & 3, wk = w >> 2;
  const int lq = l & 31, hi = l >> 5;
  const size_t base = (size_t)bh * SEQ_T * 64;
  const float CE = 0.18033688f;   // 0.125 * log2(e)
  const float DTHR = 44.3614f;    // 8 / CE

  const int qrow = qt * 128 + wq * 32 + lq;
  short8 qf[4];
#pragma unroll
  for (int c = 0; c < 4; ++c)
    qf[c] = *(const short8*)&Q[base + (size_t)qrow * 64 + c * 16 + hi * 8];

  const int r0 = tid >> 3, c8 = tid & 7;
  const unsigned short* ks0 = Kg + base + (size_t)r0 * 64 + ((c8 ^ (r0 & 7)) * 8);
  const unsigned short* vs0 = VT + base + (size_t)r0 * 2048 + ((c8 ^ (r0 & 7)) * 8);

  float mi = -1.0e30f, li = 0.f;           // li is PER-HALF until epilogue
  f32x16 oc0, oc1;
#pragma unroll
  for (int r = 0; r < 16; ++r) { oc0[r] = 0.f; oc1[r] = 0.f; }

  const int nit = qt + 1;
  const int kt0 = sp * nit;
  const int mfrom = 2 * qt;

  // prologue: K(kt0)->K0, K(kt0+1)->K1, V(kt0)->V0; full drain once.
  gl_lds16(ks0 + (size_t)kt0 * 4096, &smem[w * 512]);
  if (nit > 1) gl_lds16(ks0 + (size_t)(kt0 + 1) * 4096, &smem[4096 + w * 512]);
  gl_lds16(vs0 + (size_t)kt0 * 64, &smem[12288 + w * 512]);
  __syncthreads();

  int kcur = 0;                            // it % 3 (K read buffer)
  for (int it = 0; it < nit; ++it) {
    const int kt = kt0 + it;
    // stage V(it+1) into V[cur^1]; stage K(it+2) into the buffer vacated at it-1
    if (it + 1 < nit)
      gl_lds16(vs0 + (size_t)(kt + 1) * 64, &smem[12288 + (((it + 1) & 1)) * 4096 + w * 512]);
    if (it + 2 < nit) {
      const int kst = (kcur == 0) ? 2 : kcur - 1;   // (it+2)%3
      gl_lds16(ks0 + (size_t)(kt + 2) * 4096, &smem[kst * 4096 + w * 512]);
    }
    const unsigned short* kb = &smem[kcur * 4096];
    const unsigned short* vb = &smem[12288 + (it & 1) * 4096];

    // S^T = K Q^T over this wave's 32-kv half
    f32x16 st;
#pragma unroll
    for (int r = 0; r < 16; ++r) st[r] = 0.f;
    __builtin_amdgcn_s_setprio(1);
#pragma unroll
    for (int c = 0; c < 4; ++c) {
      const short8 kf = *(const short8*)&kb[(wk * 32 + lq) * 64 + (((2 * c + hi) ^ (lq & 7)) * 8)];
      st = __builtin_amdgcn_mfma_f32_32x32x16_bf16(kf, qf[c], st, 0, 0, 0);
    }
    __builtin_amdgcn_s_setprio(0);

    if (kt >= mfrom) {                      // causal mask (unscaled scores)
#pragma unroll
      for (int r = 0; r < 16; ++r) {
        int kvg = kt * 64 + wk * 32 + (r & 3) + 8 * (r >> 2) + 4 * hi;
        if (kvg > qrow) st[r] = -3.0e38f;
      }
    }

    // online softmax (in-register; cross-half max via permlane)
    float tm = xhalf_max(vmax16(st));
    if (!__all(tm <= mi + DTHR)) {          // T13 defer-rescale
      float mn = fmaxf(mi, tm);
      float scq = exp2f((mi - mn) * CE);
      mi = mn;
      li *= scq;
#pragma unroll
      for (int r = 0; r < 16; ++r) {
        float sc_r = __shfl(scq, (r & 3) + 8 * (r >> 2) + 4 * hi, 64);
        oc0[r] *= sc_r;
        oc1[r] *= sc_r;
      }
    }
    const float nb = mi * CE;
    float rs = 0.f;
#pragma unroll
    for (int r = 0; r < 16; ++r) {
      float p = exp2f(fmaf(st[r], CE, -nb));
      st[r] = p;
      rs += p;
    }
    li += rs;                               // per-half; combined at epilogue

    // pack P into PV A-fragments
    short8 pa[2];
#pragma unroll
    for (int kc = 0; kc < 2; ++kc) {
      const int o = kc * 8;
      unsigned w0 = cvtpk(st[o + 0], st[o + 1]);
      unsigned w1 = cvtpk(st[o + 2], st[o + 3]);
      unsigned w2 = cvtpk(st[o + 4], st[o + 5]);
      unsigned w3 = cvtpk(st[o + 6], st[o + 7]);
      plswap(w0, w2);
      plswap(w1, w3);
      uint4 F;
      F.x = w0; F.y = w1; F.z = w2; F.w = w3;
      pa[kc] = __builtin_bit_cast(short8, F);
    }

    // O += P V over this wave's 32-kv half
    {
      short8 vbf[2][2];
#pragma unroll
      for (int dt = 0; dt < 2; ++dt)
#pragma unroll
        for (int kc = 0; kc < 2; ++kc)
          vbf[dt][kc] = *(const short8*)&vb[(dt * 32 + lq) * 64 +
                          (((wk * 4 + kc * 2 + hi) ^ (lq & 7)) * 8)];
      __builtin_amdgcn_s_setprio(1);
#pragma unroll
      for (int kc = 0; kc < 2; ++kc) {
        oc0 = __builtin_amdgcn_mfma_f32_32x32x16_bf16(pa[kc], vbf[0][kc], oc0, 0, 0, 0);
        oc1 = __builtin_amdgcn_mfma_f32_32x32x16_bf16(pa[kc], vbf[1][kc], oc1, 0, 0, 0);
      }
      __builtin_amdgcn_s_setprio(0);
    }

    // counted-vmcnt barrier: wait K(it+1)+V(it+1), leave K(it+2) in flight (T4)
    if (it + 1 < nit) {
      if (it + 2 < nit) asm volatile("s_waitcnt vmcnt(1)" ::: "memory");
      else              asm volatile("s_waitcnt vmcnt(0)" ::: "memory");
      __builtin_amdgcn_s_barrier();
      __builtin_amdgcn_sched_barrier(0);
    }
    kcur = (kcur == 2) ? 0 : kcur + 1;
  }

  li = xhalf_add(li);                       // combine the two lane-half partial sums

  // ---- epilogue: merge wk halves, write NORMALIZED bf16 partial + (m, l) ----
  __syncthreads();
  float* obuf = (float*)smem;               // [wq][32 q][64 d] fp32 = 32 KB
  float* mlb  = (float*)&smem[16384];       // [wq][32 q][2] (m, l) = 1 KB (bytes 32K..33K)
  if (wk == 1) {
#pragma unroll
    for (int r = 0; r < 16; ++r) {
      const int q = (r & 3) + 8 * (r >> 2) + 4 * hi;
      obuf[wq * 2048 + q * 64 + lq]      = oc0[r];
      obuf[wq * 2048 + q * 64 + 32 + lq] = oc1[r];
    }
    if (hi == 0) {
      mlb[wq * 64 + lq * 2 + 0] = mi;
      mlb[wq * 64 + lq * 2 + 1] = li;
    }
  }
  __syncthreads();
  if (wk == 0) {
    unsigned short* dst = sp ? P1 : P0;
    const int hh = bh & 15, bb = bh >> 4;
#pragma unroll
    for (int r = 0; r < 16; ++r) {
      const int q = (r & 3) + 8 * (r >> 2) + 4 * hi;
      float m0 = __shfl(mi, q, 64), l0 = __shfl(li, q, 64);
      float m1 = mlb[wq * 64 + q * 2 + 0], l1 = mlb[wq * 64 + q * 2 + 1];
      float mm = fmaxf(m0, m1);
      float f0 = exp2f((m0 - mm) * CE), f1 = exp2f((m1 - mm) * CE);
      float dn = f0 * l0 + f1 * l1;
      float inv = (dn > 0.f) ? (1.0f / dn) : 0.f;
      float o0 = (f0 * oc0[r] + f1 * obuf[wq * 2048 + q * 64 + lq]) * inv;
      float o1 = (f0 * oc1[r] + f1 * obuf[wq * 2048 + q * 64 + 32 + lq]) * inv;
      int qg = qt * 128 + wq * 32 + q;
      size_t ob = (size_t)(bb * 2048 + qg) * 1024 + hh * 64;
      dst[ob + lq]      = f2bf(o0);
      dst[ob + 32 + lq] = f2bf(o1);
      if (lq == 0) ML[(size_t)(sp * 32 + bh) * 2048 + qg] = make_float2(mm, dn);
    }
  }
}

// ---------- combine the two kv-splits: O = (w0*O0 + w1*O1), in place on P0 ----------
__global__ void k_combine(const unsigned short* __restrict__ P1,
                          const float2* __restrict__ ML,
                          unsigned short* __restrict__ P0) {
  const float CE = 0.18033688f;
  int idx = blockIdx.x * 256 + threadIdx.x;
  int flat = idx * 8;
  int c = flat & 1023, t = (flat >> 10) & 2047, b = flat >> 21;
  int bh = b * 16 + (c >> 6);
  float2 a0 = ML[(size_t)bh * 2048 + t];
  float2 a1 = ML[(size_t)(32 + bh) * 2048 + t];
  float mm = fmaxf(a0.x, a1.x);
  float w0 = exp2f((a0.x - mm) * CE) * a0.y;
  float w1 = exp2f((a1.x - mm) * CE) * a1.y;
  float inv = 1.0f / (w0 + w1);
  w0 *= inv; w1 *= inv;
  short8 o0 = *(const short8*)&P0[flat];
  short8 o1 = *(const short8*)&P1[flat];
  short8 o;
#pragma unroll
  for (int k = 0; k < 8; ++k)
    o[k] = (short)f2bf(w0 * bf2f((unsigned short)o0[k]) + w1 * bf2f((unsigned short)o1[k]));
  *(short8*)&P0[flat] = o;
}

// ---------- GEMM2: out = attn_out @ W_proj^T + b (fp32 out) ----------
// 64x128 tile, grid (8 bn, 64 bm) = 512 blocks = 2/CU (R11-proven).
__global__ void k_gemm_proj(const unsigned short* __restrict__ A,
                            const unsigned short* __restrict__ Bt,
                            const float* __restrict__ bias,
                            float* __restrict__ out) {
  __shared__ unsigned short lA[64 * 32];
  __shared__ unsigned short lB[128 * 32];
  const int K = 1024;
  const int bn = blockIdx.x, bm = blockIdx.y;
  const int tid = threadIdx.x, w = tid >> 6, l = tid & 63;
  const int lr = l & 15, lh = l >> 4;
  const int wm = w >> 1, wn = w & 1;      // 2x2 waves over 64 rows x 128 cols

  f32x4 acc[2][4];
#pragma unroll
  for (int m = 0; m < 2; ++m)
#pragma unroll
    for (int n = 0; n < 4; ++n)
#pragma unroll
      for (int i = 0; i < 4; ++i) acc[m][n][i] = 0.f;

  const unsigned short* ga0 = A + (size_t)(bm * 64 + (tid >> 2)) * K + (tid & 3) * 8;
  const unsigned short* gb0 = Bt + (size_t)(bn * 128 + w * 16 + (l >> 2)) * K + (l & 3) * 8;
  unsigned short* la0 = &lA[w * 512];
  unsigned short* lb0 = &lB[w * 512];
  unsigned short* lb1 = &lB[(w + 4) * 512];

  for (int kt = 0; kt < K; kt += 32) {
    gl_lds16(ga0 + kt, la0);
    gl_lds16(gb0 + kt, lb0);
    gl_lds16(gb0 + (size_t)64 * K + kt, lb1);
    __syncthreads();
    short8 af[2], bf[4];
#pragma unroll
    for (int m = 0; m < 2; ++m) af[m] = *(const short8*)&lA[(wm * 32 + m * 16 + lr) * 32 + lh * 8];
#pragma unroll
    for (int n = 0; n < 4; ++n) bf[n] = *(const short8*)&lB[(wn * 64 + n * 16 + lr) * 32 + lh * 8];
#pragma unroll
    for (int m = 0; m < 2; ++m)
#pragma unroll
      for (int n = 0; n < 4; ++n)
        acc[m][n] = __builtin_amdgcn_mfma_f32_16x16x32_bf16(af[m], bf[n], acc[m][n], 0, 0, 0);
    __syncthreads();
  }

  const int col0 = bn * 128 + wn * 64;
  const int row0 = bm * 64 + wm * 32;
  float bl[4];
#pragma unroll
  for (int n = 0; n < 4; ++n) bl[n] = bias[col0 + n * 16 + lr];
#pragma unroll
  for (int m = 0; m < 2; ++m)
#pragma unroll
    for (int i = 0; i < 4; ++i) {
      int row = row0 + m * 16 + lh * 4 + i;
#pragma unroll
      for (int n = 0; n < 4; ++n)
        out[(size_t)row * 1024 + col0 + n * 16 + lr] = acc[m][n][i] + bl[n];
    }
}

extern "C" void kernel_launch(void* const* d_in, const int* in_sizes, int n_in,
                              void* d_out, int out_size, void* d_ws, size_t ws_size,
                              hipStream_t stream) {
  const float* x     = (const float*)d_in[0];
  const float* Wattn = (const float*)d_in[1];
  const float* battn = (const float*)d_in[2];
  const float* Wproj = (const float*)d_in[3];
  const float* bproj = (const float*)d_in[4];
  float* out = (float*)d_out;

  char* ws = (char*)d_ws;
  unsigned short* xb  = (unsigned short*)(ws);                  // 8 MB  x bf16 -> sp1 partial
  unsigned short* wat = (unsigned short*)(ws + (8ull  << 20));  // 6 MB  W_attn^T -> ML (1MB)
  unsigned short* wpt = (unsigned short*)(ws + (14ull << 20));  // 2 MB
  unsigned short* qa  = (unsigned short*)(ws + (16ull << 20));  // 8 MB
  unsigned short* ka  = (unsigned short*)(ws + (24ull << 20));  // 8 MB
  unsigned short* va  = (unsigned short*)(ws + (32ull << 20));  // 8 MB  V^T [BH][D][T]
  unsigned short* ob  = (unsigned short*)(ws + (40ull << 20));  // 8 MB  sp0 partial / attn out
  float2* cs          = (float2*)(ws + (48ull << 20));          // 512 KB
  float2* ml          = (float2*)wat;                           // 1 MB (wat dead after GEMM1)

  k_prep<<<6400, 256, 0, stream>>>(x, Wattn, Wproj, xb, wat, wpt, cs);
  k_gemm_qkv<<<dim3(24, 32), 256, 0, stream>>>(xb, wat, battn, cs, qa, ka, va);
  k_attn<<<1024, 512, 0, stream>>>(qa, ka, va, ob, xb, ml);
  k_combine<<<2048, 256, 0, stream>>>(xb, ml, ob);
  k_gemm_proj<<<dim3(8, 64), 256, 0, stream>>>(ob, wpt, bproj, out);
}

// Round 16
// 116.988 us; speedup vs baseline: 1.4215x; 1.0679x over previous
//
#include <hip/hip_runtime.h>
#include <cstdint>
#include <cstddef>

// Problem constants: B=2, T=2048, C=1024, H=16, D=64
#define SEQ_T 2048
#define NHEAD 16

typedef __attribute__((ext_vector_type(8))) short short8;
typedef __attribute__((ext_vector_type(4))) float f32x4;
typedef __attribute__((ext_vector_type(16))) float f32x16;

__device__ __forceinline__ unsigned short f2bf(float f) {
  union { float f; unsigned int u; } v; v.f = f;
  return (unsigned short)((v.u + 0x7FFFu + ((v.u >> 16) & 1u)) >> 16);
}
__device__ __forceinline__ float bf2f(unsigned short u) {
  union { unsigned int u; float f; } v; v.u = ((unsigned int)u) << 16;
  return v.f;
}

// raw hardware exp2: single v_exp_f32 (1-ULP, flushes denorm result to 0 --
// exactly right for softmax probabilities; avoids libm's ~6-instr guard seq)
#if __has_builtin(__builtin_amdgcn_exp2f)
__device__ __forceinline__ float hexp2(float x) { return __builtin_amdgcn_exp2f(x); }
#else
__device__ __forceinline__ float hexp2(float x) {
  float r;
  asm("v_exp_f32 %0, %1" : "=v"(r) : "v"(x));
  return r;
}
#endif

__device__ __forceinline__ unsigned cvtpk(float lo, float hi) {
  unsigned r;
  asm("v_cvt_pk_bf16_f32 %0, %1, %2" : "=v"(r) : "v"(lo), "v"(hi));
  return r;
}

__device__ __forceinline__ float max3f(float a, float b, float c) {
  float r;
  asm("v_max3_f32 %0, %1, %2, %3" : "=v"(r) : "v"(a), "v"(b), "v"(c));
  return r;
}

// permlane32_swap via builtin (compiler inserts the required hazard waits)
#if __has_builtin(__builtin_amdgcn_permlane32_swap)
__device__ __forceinline__ void plswap(unsigned& a, unsigned& b) {
  auto r = __builtin_amdgcn_permlane32_swap(a, b, false, false);
  a = r[0];
  b = r[1];
}
#else
__device__ __forceinline__ void plswap(unsigned& a, unsigned& b) {
  asm volatile("s_nop 1\n\tv_permlane32_swap_b32 %0, %1\n\ts_nop 1"
               : "+v"(a), "+v"(b));
}
#endif

__device__ __forceinline__ float xhalf_max(float x) {
  unsigned a = __builtin_bit_cast(unsigned, x), b = a;
  plswap(a, b);
  return fmaxf(__builtin_bit_cast(float, a), __builtin_bit_cast(float, b));
}
__device__ __forceinline__ float xhalf_add(float x) {
  unsigned a = __builtin_bit_cast(unsigned, x), b = a;
  plswap(a, b);
  return __builtin_bit_cast(float, a) + __builtin_bit_cast(float, b);
}

// max of 16 via v_max3 tree (T17)
__device__ __forceinline__ float vmax16(const f32x16 v) {
  float m0 = max3f(v[0], v[1], v[2]);
  float m1 = max3f(v[3], v[4], v[5]);
  float m2 = max3f(v[6], v[7], v[8]);
  float m3 = max3f(v[9], v[10], v[11]);
  float m4 = max3f(v[12], v[13], v[14]);
  float m5 = max3f(m0, m1, v[15]);
  float m6 = max3f(m2, m3, m4);
  return fmaxf(m5, m6);
}

__device__ __forceinline__ void gl_lds16(const void* g, void* l) {
  __builtin_amdgcn_global_load_lds(
      (__attribute__((address_space(1))) void*)(void*)g,
      (__attribute__((address_space(3))) void*)l, 16, 0, 0);
}

// ---------- fused prep: fp32->bf16 cvt, 2x transpose-convert, RoPE table ----------
__global__ void k_prep(const float* __restrict__ x,
                       const float* __restrict__ Wa,
                       const float* __restrict__ Wp,
                       unsigned short* __restrict__ xb,
                       unsigned short* __restrict__ wat,
                       unsigned short* __restrict__ wpt,
                       float2* __restrict__ tab) {
  const int b = blockIdx.x, tid = threadIdx.x;
  if (b < 4096) {                       // x cvt: 1M threads x float4
    int i = b * 256 + tid;
    float4 v = ((const float4*)x)[i];
    unsigned long long pk = (unsigned long long)f2bf(v.x)
                          | ((unsigned long long)f2bf(v.y) << 16)
                          | ((unsigned long long)f2bf(v.z) << 32)
                          | ((unsigned long long)f2bf(v.w) << 48);
    ((unsigned long long*)xb)[i] = pk;
  } else if (b < 5632) {                // W_attn [1024,3072] -> [3072,1024]
    int idx = (b - 4096) * 256 + tid;
    int n = idx % 3072, k0 = (idx / 3072) * 8;
    short8 v;
#pragma unroll
    for (int j = 0; j < 8; ++j)
      v[j] = (short)f2bf(Wa[(size_t)(k0 + j) * 3072 + n]);
    *(short8*)&wat[(size_t)n * 1024 + k0] = v;
  } else if (b < 6144) {                // W_proj [1024,1024] -> transpose
    int idx = (b - 5632) * 256 + tid;
    int n = idx & 1023, k0 = (idx >> 10) * 8;
    short8 v;
#pragma unroll
    for (int j = 0; j < 8; ++j)
      v[j] = (short)f2bf(Wp[(size_t)(k0 + j) * 1024 + n]);
    *(short8*)&wpt[(size_t)n * 1024 + k0] = v;
  } else {                              // RoPE table [2048][32]
    int idx = (b - 6144) * 256 + tid;
    int t = idx >> 5, i = idx & 31;
    float inv = powf(10000.0f, -(float)(2 * i) / 64.0f);
    float f = (float)t * inv;
    tab[idx] = make_float2(cosf(f), sinf(f));
  }
}

// ---------- GEMM1: qkv = x @ W_attn^T(+b), fused RoPE; q/k -> [B,H,T,D], v -> V^T [B,H,D,T] ----------
__global__ void k_gemm_qkv(const unsigned short* __restrict__ A,
                           const unsigned short* __restrict__ Bt,
                           const float* __restrict__ bias,
                           const float2* __restrict__ cs,
                           unsigned short* __restrict__ qo,
                           unsigned short* __restrict__ ko,
                           unsigned short* __restrict__ vo) {
  __shared__ unsigned short lA[128 * 32];
  __shared__ unsigned short lB[128 * 32];
  const int K = 1024;
  const int bn = blockIdx.x, bm = blockIdx.y;
  const int tid = threadIdx.x, w = tid >> 6, l = tid & 63;
  const int lr = l & 15, lh = l >> 4;
  const int wm = w >> 1, wn = w & 1;

  f32x4 acc[4][4];
#pragma unroll
  for (int m = 0; m < 4; ++m)
#pragma unroll
    for (int n = 0; n < 4; ++n)
#pragma unroll
      for (int i = 0; i < 4; ++i) acc[m][n][i] = 0.f;

  const unsigned short* ga0 = A + (size_t)(bm * 128 + w * 16 + (l >> 2)) * K + (l & 3) * 8;
  const unsigned short* gb0 = Bt + (size_t)(bn * 128 + w * 16 + (l >> 2)) * K + (l & 3) * 8;
  unsigned short* la0 = &lA[w * 512];
  unsigned short* la1 = &lA[(w + 4) * 512];
  unsigned short* lb0 = &lB[w * 512];
  unsigned short* lb1 = &lB[(w + 4) * 512];

  for (int kt = 0; kt < K; kt += 32) {
    gl_lds16(ga0 + kt, la0);
    gl_lds16(ga0 + (size_t)64 * K + kt, la1);
    gl_lds16(gb0 + kt, lb0);
    gl_lds16(gb0 + (size_t)64 * K + kt, lb1);
    __syncthreads();
    short8 af[4], bf[4];
#pragma unroll
    for (int m = 0; m < 4; ++m) af[m] = *(const short8*)&lA[(wm * 64 + m * 16 + lr) * 32 + lh * 8];
#pragma unroll
    for (int n = 0; n < 4; ++n) bf[n] = *(const short8*)&lB[(wn * 64 + n * 16 + lr) * 32 + lh * 8];
#pragma unroll
    for (int m = 0; m < 4; ++m)
#pragma unroll
      for (int n = 0; n < 4; ++n)
        acc[m][n] = __builtin_amdgcn_mfma_f32_16x16x32_bf16(af[m], bf[n], acc[m][n], 0, 0, 0);
    __syncthreads();
  }

  const int col0 = bn * 128 + wn * 64;
  const int row0 = bm * 128 + wm * 64;
  const int sec = col0 >> 10;
  const int hh = (col0 >> 6) & 15;
  float bl[4];
#pragma unroll
  for (int n = 0; n < 4; ++n) bl[n] = bias[col0 + n * 16 + lr];

  if (sec == 2) {
    const int b = row0 >> 11;
    unsigned short* vtp = vo + (size_t)(b * 16 + hh) * 64 * 2048;
#pragma unroll
    for (int n = 0; n < 4; ++n) {
      int d = n * 16 + lr;
#pragma unroll
      for (int m = 0; m < 4; ++m) {
        int t = (row0 + m * 16 + lh * 4) & 2047;
        unsigned long long pk = (unsigned long long)f2bf(acc[m][n][0] + bl[n])
                              | ((unsigned long long)f2bf(acc[m][n][1] + bl[n]) << 16)
                              | ((unsigned long long)f2bf(acc[m][n][2] + bl[n]) << 32)
                              | ((unsigned long long)f2bf(acc[m][n][3] + bl[n]) << 48);
        *(unsigned long long*)&vtp[(size_t)d * 2048 + t] = pk;
      }
    }
  } else {
    unsigned short* dst = (sec == 0) ? qo : ko;
#pragma unroll
    for (int m = 0; m < 4; ++m)
#pragma unroll
      for (int i = 0; i < 4; ++i) {
        int row = row0 + m * 16 + lh * 4 + i;
        int t = row & 2047, b = row >> 11;
        size_t ob = ((size_t)(b * 16 + hh) * 2048 + t) * 64;
#pragma unroll
        for (int n = 0; n < 4; ++n) {
          float v = acc[m][n][i] + bl[n];
          float pv = acc[m][n ^ 2][i] + bl[n ^ 2];
          int d = n * 16 + lr;
          float2 c = cs[t * 32 + (d & 31)];
          float rot = (d < 32) ? -pv : pv;
          dst[ob + d] = f2bf(v * c.x + rot * c.y);
        }
      }
  }
}

// ---------- flash attention: flash-decoding kv-split, grid 1024 (R11-proven) ----------
// Block = (bh, qt, sp): sp halves the kv range. 512 thr = 8 waves (wq, wk).
// max3 tree (T17); deferred li combine; raw v_exp_f32 softmax (hexp2).
__global__ __launch_bounds__(512, 4) void k_attn(const unsigned short* __restrict__ Q,
                       const unsigned short* __restrict__ Kg,
                       const unsigned short* __restrict__ VT,
                       unsigned short* __restrict__ P0,
                       unsigned short* __restrict__ P1,
                       float2* __restrict__ ML) {
  __shared__ unsigned short smem[16896];   // 33KB: kl[2] @0, vl[2] @8192, mlb @16384
  const int id = blockIdx.x;
  const int xcd = id & 7, u = id >> 3;
  const int a = u & 31, sweep = u >> 5;
  const int g = a & 3, j = a >> 2;
  const int bh = xcd * 4 + g;
  const int qt = (sweep & 1) ? (15 - j) : j;
  const int sp = sweep >> 1;
  const int tid = threadIdx.x, w = tid >> 6, l = tid & 63;
  const int wq = w & 3, wk = w >> 2;
  const int lq = l & 31, hi = l >> 5;
  const size_t base = (size_t)bh * SEQ_T * 64;
  const float CE = 0.18033688f;   // 0.125 * log2(e)
  const float DTHR = 44.3614f;    // 8 / CE

  const int qrow = qt * 128 + wq * 32 + lq;
  short8 qf[4];
#pragma unroll
  for (int c = 0; c < 4; ++c)
    qf[c] = *(const short8*)&Q[base + (size_t)qrow * 64 + c * 16 + hi * 8];

  const int r0 = tid >> 3, c8 = tid & 7;
  const unsigned short* ks0 = Kg + base + (size_t)r0 * 64 + ((c8 ^ (r0 & 7)) * 8);
  const unsigned short* vs0 = VT + base + (size_t)r0 * 2048 + ((c8 ^ (r0 & 7)) * 8);

#define STAGE(KT, B) do { \
    gl_lds16(ks0 + (size_t)(KT) * 4096, &smem[(B) * 4096 + w * 512]); \
    gl_lds16(vs0 + (size_t)(KT) * 64,   &smem[8192 + (B) * 4096 + w * 512]); \
  } while (0)

  float mi = -1.0e30f, li = 0.f;           // li is PER-HALF until epilogue
  f32x16 oc0, oc1;
#pragma unroll
  for (int r = 0; r < 16; ++r) { oc0[r] = 0.f; oc1[r] = 0.f; }

  const int nit = qt + 1;
  const int kt0 = sp * nit;
  const int mfrom = 2 * qt;
  STAGE(kt0, 0);
  __syncthreads();

  for (int it = 0; it < nit; ++it) {
    const int cur = it & 1;
    const int kt = kt0 + it;
    if (it + 1 < nit) STAGE(kt + 1, cur ^ 1);
    const unsigned short* kb = &smem[cur * 4096];
    const unsigned short* vb = &smem[8192 + cur * 4096];

    // S^T = K Q^T over this wave's 32-kv half
    f32x16 st;
#pragma unroll
    for (int r = 0; r < 16; ++r) st[r] = 0.f;
    __builtin_amdgcn_s_setprio(1);
#pragma unroll
    for (int c = 0; c < 4; ++c) {
      const short8 kf = *(const short8*)&kb[(wk * 32 + lq) * 64 + (((2 * c + hi) ^ (lq & 7)) * 8)];
      st = __builtin_amdgcn_mfma_f32_32x32x16_bf16(kf, qf[c], st, 0, 0, 0);
    }
    __builtin_amdgcn_s_setprio(0);

    if (kt >= mfrom) {                      // causal mask (unscaled scores)
#pragma unroll
      for (int r = 0; r < 16; ++r) {
        int kvg = kt * 64 + wk * 32 + (r & 3) + 8 * (r >> 2) + 4 * hi;
        if (kvg > qrow) st[r] = -3.0e38f;
      }
    }

    // online softmax (in-register; cross-half max via permlane)
    float tm = xhalf_max(vmax16(st));
    if (!__all(tm <= mi + DTHR)) {          // T13 defer-rescale
      float mn = fmaxf(mi, tm);
      float scq = hexp2((mi - mn) * CE);
      mi = mn;
      li *= scq;
#pragma unroll
      for (int r = 0; r < 16; ++r) {
        float sc_r = __shfl(scq, (r & 3) + 8 * (r >> 2) + 4 * hi, 64);
        oc0[r] *= sc_r;
        oc1[r] *= sc_r;
      }
    }
    const float nb = mi * CE;
    float rs = 0.f;
#pragma unroll
    for (int r = 0; r < 16; ++r) {
      float p = hexp2(fmaf(st[r], CE, -nb));
      st[r] = p;
      rs += p;
    }
    li += rs;                               // per-half; combined at epilogue

    // pack P into PV A-fragments
    short8 pa[2];
#pragma unroll
    for (int kc = 0; kc < 2; ++kc) {
      const int o = kc * 8;
      unsigned w0 = cvtpk(st[o + 0], st[o + 1]);
      unsigned w1 = cvtpk(st[o + 2], st[o + 3]);
      unsigned w2 = cvtpk(st[o + 4], st[o + 5]);
      unsigned w3 = cvtpk(st[o + 6], st[o + 7]);
      plswap(w0, w2);
      plswap(w1, w3);
      uint4 F;
      F.x = w0; F.y = w1; F.z = w2; F.w = w3;
      pa[kc] = __builtin_bit_cast(short8, F);
    }

    // O += P V over this wave's 32-kv half
    {
      short8 vbf[2][2];
#pragma unroll
      for (int dt = 0; dt < 2; ++dt)
#pragma unroll
        for (int kc = 0; kc < 2; ++kc)
          vbf[dt][kc] = *(const short8*)&vb[(dt * 32 + lq) * 64 +
                          (((wk * 4 + kc * 2 + hi) ^ (lq & 7)) * 8)];
      __builtin_amdgcn_s_setprio(1);
#pragma unroll
      for (int kc = 0; kc < 2; ++kc) {
        oc0 = __builtin_amdgcn_mfma_f32_32x32x16_bf16(pa[kc], vbf[0][kc], oc0, 0, 0, 0);
        oc1 = __builtin_amdgcn_mfma_f32_32x32x16_bf16(pa[kc], vbf[1][kc], oc1, 0, 0, 0);
      }
      __builtin_amdgcn_s_setprio(0);
    }

    if (it + 1 < nit) __syncthreads();
  }

  li = xhalf_add(li);                       // combine the two lane-half partial sums

  // ---- epilogue: merge wk halves, write NORMALIZED bf16 partial + (m, l) ----
  __syncthreads();
  float* obuf = (float*)smem;               // [wq][32 q][64 d] fp32 = 32 KB
  float* mlb  = (float*)&smem[16384];       // [wq][32 q][2] (m, l) = 1 KB
  if (wk == 1) {
#pragma unroll
    for (int r = 0; r < 16; ++r) {
      const int q = (r & 3) + 8 * (r >> 2) + 4 * hi;
      obuf[wq * 2048 + q * 64 + lq]      = oc0[r];
      obuf[wq * 2048 + q * 64 + 32 + lq] = oc1[r];
    }
    if (hi == 0) {
      mlb[wq * 64 + lq * 2 + 0] = mi;
      mlb[wq * 64 + lq * 2 + 1] = li;
    }
  }
  __syncthreads();
  if (wk == 0) {
    unsigned short* dst = sp ? P1 : P0;
    const int hh = bh & 15, bb = bh >> 4;
#pragma unroll
    for (int r = 0; r < 16; ++r) {
      const int q = (r & 3) + 8 * (r >> 2) + 4 * hi;
      float m0 = __shfl(mi, q, 64), l0 = __shfl(li, q, 64);
      float m1 = mlb[wq * 64 + q * 2 + 0], l1 = mlb[wq * 64 + q * 2 + 1];
      float mm = fmaxf(m0, m1);
      float f0 = hexp2((m0 - mm) * CE), f1 = hexp2((m1 - mm) * CE);
      float dn = f0 * l0 + f1 * l1;
      float inv = (dn > 0.f) ? (1.0f / dn) : 0.f;
      float o0 = (f0 * oc0[r] + f1 * obuf[wq * 2048 + q * 64 + lq]) * inv;
      float o1 = (f0 * oc1[r] + f1 * obuf[wq * 2048 + q * 64 + 32 + lq]) * inv;
      int qg = qt * 128 + wq * 32 + q;
      size_t ob = (size_t)(bb * 2048 + qg) * 1024 + hh * 64;
      dst[ob + lq]      = f2bf(o0);
      dst[ob + 32 + lq] = f2bf(o1);
      if (lq == 0) ML[(size_t)(sp * 32 + bh) * 2048 + qg] = make_float2(mm, dn);
    }
  }
#undef STAGE
}

// ---------- combine the two kv-splits: O = (w0*O0 + w1*O1), in place on P0 ----------
__global__ void k_combine(const unsigned short* __restrict__ P1,
                          const float2* __restrict__ ML,
                          unsigned short* __restrict__ P0) {
  const float CE = 0.18033688f;
  int idx = blockIdx.x * 256 + threadIdx.x;
  int flat = idx * 8;
  int c = flat & 1023, t = (flat >> 10) & 2047, b = flat >> 21;
  int bh = b * 16 + (c >> 6);
  float2 a0 = ML[(size_t)bh * 2048 + t];
  float2 a1 = ML[(size_t)(32 + bh) * 2048 + t];
  float mm = fmaxf(a0.x, a1.x);
  float w0 = hexp2((a0.x - mm) * CE) * a0.y;
  float w1 = hexp2((a1.x - mm) * CE) * a1.y;
  float inv = 1.0f / (w0 + w1);
  w0 *= inv; w1 *= inv;
  short8 o0 = *(const short8*)&P0[flat];
  short8 o1 = *(const short8*)&P1[flat];
  short8 o;
#pragma unroll
  for (int k = 0; k < 8; ++k)
    o[k] = (short)f2bf(w0 * bf2f((unsigned short)o0[k]) + w1 * bf2f((unsigned short)o1[k]));
  *(short8*)&P0[flat] = o;
}

// ---------- GEMM2: out = attn_out @ W_proj^T + b (fp32 out) ----------
// 64x128 tile, grid (8 bn, 64 bm) = 512 blocks = 2/CU (R11-proven).
__global__ void k_gemm_proj(const unsigned short* __restrict__ A,
                            const unsigned short* __restrict__ Bt,
                            const float* __restrict__ bias,
                            float* __restrict__ out) {
  __shared__ unsigned short lA[64 * 32];
  __shared__ unsigned short lB[128 * 32];
  const int K = 1024;
  const int bn = blockIdx.x, bm = blockIdx.y;
  const int tid = threadIdx.x, w = tid >> 6, l = tid & 63;
  const int lr = l & 15, lh = l >> 4;
  const int wm = w >> 1, wn = w & 1;      // 2x2 waves over 64 rows x 128 cols

  f32x4 acc[2][4];
#pragma unroll
  for (int m = 0; m < 2; ++m)
#pragma unroll
    for (int n = 0; n < 4; ++n)
#pragma unroll
      for (int i = 0; i < 4; ++i) acc[m][n][i] = 0.f;

  const unsigned short* ga0 = A + (size_t)(bm * 64 + (tid >> 2)) * K + (tid & 3) * 8;
  const unsigned short* gb0 = Bt + (size_t)(bn * 128 + w * 16 + (l >> 2)) * K + (l & 3) * 8;
  unsigned short* la0 = &lA[w * 512];
  unsigned short* lb0 = &lB[w * 512];
  unsigned short* lb1 = &lB[(w + 4) * 512];

  for (int kt = 0; kt < K; kt += 32) {
    gl_lds16(ga0 + kt, la0);
    gl_lds16(gb0 + kt, lb0);
    gl_lds16(gb0 + (size_t)64 * K + kt, lb1);
    __syncthreads();
    short8 af[2], bf[4];
#pragma unroll
    for (int m = 0; m < 2; ++m) af[m] = *(const short8*)&lA[(wm * 32 + m * 16 + lr) * 32 + lh * 8];
#pragma unroll
    for (int n = 0; n < 4; ++n) bf[n] = *(const short8*)&lB[(wn * 64 + n * 16 + lr) * 32 + lh * 8];
#pragma unroll
    for (int m = 0; m < 2; ++m)
#pragma unroll
      for (int n = 0; n < 4; ++n)
        acc[m][n] = __builtin_amdgcn_mfma_f32_16x16x32_bf16(af[m], bf[n], acc[m][n], 0, 0, 0);
    __syncthreads();
  }

  const int col0 = bn * 128 + wn * 64;
  const int row0 = bm * 64 + wm * 32;
  float bl[4];
#pragma unroll
  for (int n = 0; n < 4; ++n) bl[n] = bias[col0 + n * 16 + lr];
#pragma unroll
  for (int m = 0; m < 2; ++m)
#pragma unroll
    for (int i = 0; i < 4; ++i) {
      int row = row0 + m * 16 + lh * 4 + i;
#pragma unroll
      for (int n = 0; n < 4; ++n)
        out[(size_t)row * 1024 + col0 + n * 16 + lr] = acc[m][n][i] + bl[n];
    }
}

extern "C" void kernel_launch(void* const* d_in, const int* in_sizes, int n_in,
                              void* d_out, int out_size, void* d_ws, size_t ws_size,
                              hipStream_t stream) {
  const float* x     = (const float*)d_in[0];
  const float* Wattn = (const float*)d_in[1];
  const float* battn = (const float*)d_in[2];
  const float* Wproj = (const float*)d_in[3];
  const float* bproj = (const float*)d_in[4];
  float* out = (float*)d_out;

  char* ws = (char*)d_ws;
  unsigned short* xb  = (unsigned short*)(ws);                  // 8 MB  x bf16 -> sp1 partial
  unsigned short* wat = (unsigned short*)(ws + (8ull  << 20));  // 6 MB  W_attn^T -> ML (1MB)
  unsigned short* wpt = (unsigned short*)(ws + (14ull << 20));  // 2 MB
  unsigned short* qa  = (unsigned short*)(ws + (16ull << 20));  // 8 MB
  unsigned short* ka  = (unsigned short*)(ws + (24ull << 20));  // 8 MB
  unsigned short* va  = (unsigned short*)(ws + (32ull << 20));  // 8 MB  V^T [BH][D][T]
  unsigned short* ob  = (unsigned short*)(ws + (40ull << 20));  // 8 MB  sp0 partial / attn out
  float2* cs          = (float2*)(ws + (48ull << 20));          // 512 KB
  float2* ml          = (float2*)wat;                           // 1 MB (wat dead after GEMM1)

  k_prep<<<6400, 256, 0, stream>>>(x, Wattn, Wproj, xb, wat, wpt, cs);
  k_gemm_qkv<<<dim3(24, 32), 256, 0, stream>>>(xb, wat, battn, cs, qa, ka, va);
  k_attn<<<1024, 512, 0, stream>>>(qa, ka, va, ob, xb, ml);
  k_combine<<<2048, 256, 0, stream>>>(xb, ml, ob);
  k_gemm_proj<<<dim3(8, 64), 256, 0, stream>>>(ob, wpt, bproj, out);
}

// Round 17
// 114.921 us; speedup vs baseline: 1.4471x; 1.0180x over previous
//
#include <hip/hip_runtime.h>
#include <cstdint>
#include <cstddef>

// Problem constants: B=2, T=2048, C=1024, H=16, D=64
#define SEQ_T 2048
#define NHEAD 16

typedef __attribute__((ext_vector_type(8))) short short8;
typedef __attribute__((ext_vector_type(4))) float f32x4;
typedef __attribute__((ext_vector_type(16))) float f32x16;

__device__ __forceinline__ unsigned short f2bf(float f) {
  union { float f; unsigned int u; } v; v.f = f;
  return (unsigned short)((v.u + 0x7FFFu + ((v.u >> 16) & 1u)) >> 16);
}
__device__ __forceinline__ float bf2f(unsigned short u) {
  union { unsigned int u; float f; } v; v.u = ((unsigned int)u) << 16;
  return v.f;
}

// raw hardware exp2 (R16-proven: removes libm guard sequence)
#if __has_builtin(__builtin_amdgcn_exp2f)
__device__ __forceinline__ float hexp2(float x) { return __builtin_amdgcn_exp2f(x); }
#else
__device__ __forceinline__ float hexp2(float x) {
  float r;
  asm("v_exp_f32 %0, %1" : "=v"(r) : "v"(x));
  return r;
}
#endif

__device__ __forceinline__ unsigned cvtpk(float lo, float hi) {
  unsigned r;
  asm("v_cvt_pk_bf16_f32 %0, %1, %2" : "=v"(r) : "v"(lo), "v"(hi));
  return r;
}

__device__ __forceinline__ float max3f(float a, float b, float c) {
  float r;
  asm("v_max3_f32 %0, %1, %2, %3" : "=v"(r) : "v"(a), "v"(b), "v"(c));
  return r;
}

// permlane32_swap via builtin (compiler inserts the required hazard waits)
#if __has_builtin(__builtin_amdgcn_permlane32_swap)
__device__ __forceinline__ void plswap(unsigned& a, unsigned& b) {
  auto r = __builtin_amdgcn_permlane32_swap(a, b, false, false);
  a = r[0];
  b = r[1];
}
#else
__device__ __forceinline__ void plswap(unsigned& a, unsigned& b) {
  asm volatile("s_nop 1\n\tv_permlane32_swap_b32 %0, %1\n\ts_nop 1"
               : "+v"(a), "+v"(b));
}
#endif

__device__ __forceinline__ float xhalf_max(float x) {
  unsigned a = __builtin_bit_cast(unsigned, x), b = a;
  plswap(a, b);
  return fmaxf(__builtin_bit_cast(float, a), __builtin_bit_cast(float, b));
}
__device__ __forceinline__ float xhalf_add(float x) {
  unsigned a = __builtin_bit_cast(unsigned, x), b = a;
  plswap(a, b);
  return __builtin_bit_cast(float, a) + __builtin_bit_cast(float, b);
}

// max of 16 via v_max3 tree (T17)
__device__ __forceinline__ float vmax16(const f32x16 v) {
  float m0 = max3f(v[0], v[1], v[2]);
  float m1 = max3f(v[3], v[4], v[5]);
  float m2 = max3f(v[6], v[7], v[8]);
  float m3 = max3f(v[9], v[10], v[11]);
  float m4 = max3f(v[12], v[13], v[14]);
  float m5 = max3f(m0, m1, v[15]);
  float m6 = max3f(m2, m3, m4);
  return fmaxf(m5, m6);
}

__device__ __forceinline__ void gl_lds16(const void* g, void* l) {
  __builtin_amdgcn_global_load_lds(
      (__attribute__((address_space(1))) void*)(void*)g,
      (__attribute__((address_space(3))) void*)l, 16, 0, 0);
}

// ---------- fused prep: fp32->bf16 cvt, 2x transpose-convert, RoPE table ----------
__global__ void k_prep(const float* __restrict__ x,
                       const float* __restrict__ Wa,
                       const float* __restrict__ Wp,
                       unsigned short* __restrict__ xb,
                       unsigned short* __restrict__ wat,
                       unsigned short* __restrict__ wpt,
                       float2* __restrict__ tab) {
  const int b = blockIdx.x, tid = threadIdx.x;
  if (b < 4096) {                       // x cvt: 1M threads x float4
    int i = b * 256 + tid;
    float4 v = ((const float4*)x)[i];
    unsigned long long pk = (unsigned long long)f2bf(v.x)
                          | ((unsigned long long)f2bf(v.y) << 16)
                          | ((unsigned long long)f2bf(v.z) << 32)
                          | ((unsigned long long)f2bf(v.w) << 48);
    ((unsigned long long*)xb)[i] = pk;
  } else if (b < 5632) {                // W_attn [1024,3072] -> [3072,1024]
    int idx = (b - 4096) * 256 + tid;
    int n = idx % 3072, k0 = (idx / 3072) * 8;
    short8 v;
#pragma unroll
    for (int j = 0; j < 8; ++j)
      v[j] = (short)f2bf(Wa[(size_t)(k0 + j) * 3072 + n]);
    *(short8*)&wat[(size_t)n * 1024 + k0] = v;
  } else if (b < 6144) {                // W_proj [1024,1024] -> transpose
    int idx = (b - 5632) * 256 + tid;
    int n = idx & 1023, k0 = (idx >> 10) * 8;
    short8 v;
#pragma unroll
    for (int j = 0; j < 8; ++j)
      v[j] = (short)f2bf(Wp[(size_t)(k0 + j) * 1024 + n]);
    *(short8*)&wpt[(size_t)n * 1024 + k0] = v;
  } else {                              // RoPE table [2048][32]
    int idx = (b - 6144) * 256 + tid;
    int t = idx >> 5, i = idx & 31;
    float inv = powf(10000.0f, -(float)(2 * i) / 64.0f);
    float f = (float)t * inv;
    tab[idx] = make_float2(cosf(f), sinf(f));
  }
}

// ---------- GEMM1: qkv = x @ W_attn^T(+b), fused RoPE; q/k -> [B,H,T,D], v -> V^T [B,H,D,T] ----------
// BK=64, T2 chunk-XOR swizzle: staged with pre-swizzled global source (c8 ^= row&7),
// linear LDS dest; fragment ds_read_b128 XORs the same pattern -> conflict-free.
// 16 K-iterations (was 32) -> half the barrier count.
__global__ void k_gemm_qkv(const unsigned short* __restrict__ A,
                           const unsigned short* __restrict__ Bt,
                           const float* __restrict__ bias,
                           const float2* __restrict__ cs,
                           unsigned short* __restrict__ qo,
                           unsigned short* __restrict__ ko,
                           unsigned short* __restrict__ vo) {
  __shared__ unsigned short lA[128 * 64];   // 16KB, [row][8 chunks of 16B], swizzled
  __shared__ unsigned short lB[128 * 64];   // 16KB
  const int K = 1024;
  const int bn = blockIdx.x, bm = blockIdx.y;
  const int tid = threadIdx.x, w = tid >> 6, l = tid & 63;
  const int lr = l & 15, lh = l >> 4;
  const int wm = w >> 1, wn = w & 1;

  f32x4 acc[4][4];
#pragma unroll
  for (int m = 0; m < 4; ++m)
#pragma unroll
    for (int n = 0; n < 4; ++n)
#pragma unroll
      for (int i = 0; i < 4; ++i) acc[m][n][i] = 0.f;

  // staging: row = rep*32 + (tid>>3); src chunk = (tid&7) ^ ((tid>>3)&7)  (rep-invariant)
  const int srow = tid >> 3;
  const int scol = ((tid & 7) ^ (srow & 7)) * 8;
  const unsigned short* ga0 = A + (size_t)(bm * 128 + srow) * K + scol;
  const unsigned short* gb0 = Bt + (size_t)(bn * 128 + srow) * K + scol;
  unsigned short* lad = &lA[w * 512];
  unsigned short* lbd = &lB[w * 512];

  for (int kt = 0; kt < K; kt += 64) {
#pragma unroll
    for (int rep = 0; rep < 4; ++rep) {
      gl_lds16(ga0 + (size_t)rep * 32 * K + kt, lad + rep * 2048);
      gl_lds16(gb0 + (size_t)rep * 32 * K + kt, lbd + rep * 2048);
    }
    __syncthreads();
#pragma unroll
    for (int ks = 0; ks < 2; ++ks) {
      short8 af[4], bf[4];
#pragma unroll
      for (int m = 0; m < 4; ++m) {
        const int row = wm * 64 + m * 16 + lr;
        af[m] = *(const short8*)&lA[row * 64 + (((ks * 4 + lh) ^ (row & 7)) * 8)];
      }
#pragma unroll
      for (int n = 0; n < 4; ++n) {
        const int row = wn * 64 + n * 16 + lr;
        bf[n] = *(const short8*)&lB[row * 64 + (((ks * 4 + lh) ^ (row & 7)) * 8)];
      }
#pragma unroll
      for (int m = 0; m < 4; ++m)
#pragma unroll
        for (int n = 0; n < 4; ++n)
          acc[m][n] = __builtin_amdgcn_mfma_f32_16x16x32_bf16(af[m], bf[n], acc[m][n], 0, 0, 0);
    }
    __syncthreads();
  }

  const int col0 = bn * 128 + wn * 64;
  const int row0 = bm * 128 + wm * 64;
  const int sec = col0 >> 10;
  const int hh = (col0 >> 6) & 15;
  float bl[4];
#pragma unroll
  for (int n = 0; n < 4; ++n) bl[n] = bias[col0 + n * 16 + lr];

  if (sec == 2) {
    const int b = row0 >> 11;
    unsigned short* vtp = vo + (size_t)(b * 16 + hh) * 64 * 2048;
#pragma unroll
    for (int n = 0; n < 4; ++n) {
      int d = n * 16 + lr;
#pragma unroll
      for (int m = 0; m < 4; ++m) {
        int t = (row0 + m * 16 + lh * 4) & 2047;
        unsigned long long pk = (unsigned long long)f2bf(acc[m][n][0] + bl[n])
                              | ((unsigned long long)f2bf(acc[m][n][1] + bl[n]) << 16)
                              | ((unsigned long long)f2bf(acc[m][n][2] + bl[n]) << 32)
                              | ((unsigned long long)f2bf(acc[m][n][3] + bl[n]) << 48);
        *(unsigned long long*)&vtp[(size_t)d * 2048 + t] = pk;
      }
    }
  } else {
    unsigned short* dst = (sec == 0) ? qo : ko;
#pragma unroll
    for (int m = 0; m < 4; ++m)
#pragma unroll
      for (int i = 0; i < 4; ++i) {
        int row = row0 + m * 16 + lh * 4 + i;
        int t = row & 2047, b = row >> 11;
        size_t ob = ((size_t)(b * 16 + hh) * 2048 + t) * 64;
#pragma unroll
        for (int n = 0; n < 4; ++n) {
          float v = acc[m][n][i] + bl[n];
          float pv = acc[m][n ^ 2][i] + bl[n ^ 2];
          int d = n * 16 + lr;
          float2 c = cs[t * 32 + (d & 31)];
          float rot = (d < 32) ? -pv : pv;
          dst[ob + d] = f2bf(v * c.x + rot * c.y);
        }
      }
  }
}

// ---------- flash attention: flash-decoding kv-split, grid 1024 (R16-proven, UNCHANGED) ----------
__global__ __launch_bounds__(512, 4) void k_attn(const unsigned short* __restrict__ Q,
                       const unsigned short* __restrict__ Kg,
                       const unsigned short* __restrict__ VT,
                       unsigned short* __restrict__ P0,
                       unsigned short* __restrict__ P1,
                       float2* __restrict__ ML) {
  __shared__ unsigned short smem[16896];   // 33KB: kl[2] @0, vl[2] @8192, mlb @16384
  const int id = blockIdx.x;
  const int xcd = id & 7, u = id >> 3;
  const int a = u & 31, sweep = u >> 5;
  const int g = a & 3, j = a >> 2;
  const int bh = xcd * 4 + g;
  const int qt = (sweep & 1) ? (15 - j) : j;
  const int sp = sweep >> 1;
  const int tid = threadIdx.x, w = tid >> 6, l = tid & 63;
  const int wq = w & 3, wk = w >> 2;
  const int lq = l & 31, hi = l >> 5;
  const size_t base = (size_t)bh * SEQ_T * 64;
  const float CE = 0.18033688f;   // 0.125 * log2(e)
  const float DTHR = 44.3614f;    // 8 / CE

  const int qrow = qt * 128 + wq * 32 + lq;
  short8 qf[4];
#pragma unroll
  for (int c = 0; c < 4; ++c)
    qf[c] = *(const short8*)&Q[base + (size_t)qrow * 64 + c * 16 + hi * 8];

  const int r0 = tid >> 3, c8 = tid & 7;
  const unsigned short* ks0 = Kg + base + (size_t)r0 * 64 + ((c8 ^ (r0 & 7)) * 8);
  const unsigned short* vs0 = VT + base + (size_t)r0 * 2048 + ((c8 ^ (r0 & 7)) * 8);

#define STAGE(KT, B) do { \
    gl_lds16(ks0 + (size_t)(KT) * 4096, &smem[(B) * 4096 + w * 512]); \
    gl_lds16(vs0 + (size_t)(KT) * 64,   &smem[8192 + (B) * 4096 + w * 512]); \
  } while (0)

  float mi = -1.0e30f, li = 0.f;           // li is PER-HALF until epilogue
  f32x16 oc0, oc1;
#pragma unroll
  for (int r = 0; r < 16; ++r) { oc0[r] = 0.f; oc1[r] = 0.f; }

  const int nit = qt + 1;
  const int kt0 = sp * nit;
  const int mfrom = 2 * qt;
  STAGE(kt0, 0);
  __syncthreads();

  for (int it = 0; it < nit; ++it) {
    const int cur = it & 1;
    const int kt = kt0 + it;
    if (it + 1 < nit) STAGE(kt + 1, cur ^ 1);
    const unsigned short* kb = &smem[cur * 4096];
    const unsigned short* vb = &smem[8192 + cur * 4096];

    // S^T = K Q^T over this wave's 32-kv half
    f32x16 st;
#pragma unroll
    for (int r = 0; r < 16; ++r) st[r] = 0.f;
    __builtin_amdgcn_s_setprio(1);
#pragma unroll
    for (int c = 0; c < 4; ++c) {
      const short8 kf = *(const short8*)&kb[(wk * 32 + lq) * 64 + (((2 * c + hi) ^ (lq & 7)) * 8)];
      st = __builtin_amdgcn_mfma_f32_32x32x16_bf16(kf, qf[c], st, 0, 0, 0);
    }
    __builtin_amdgcn_s_setprio(0);

    if (kt >= mfrom) {                      // causal mask (unscaled scores)
#pragma unroll
      for (int r = 0; r < 16; ++r) {
        int kvg = kt * 64 + wk * 32 + (r & 3) + 8 * (r >> 2) + 4 * hi;
        if (kvg > qrow) st[r] = -3.0e38f;
      }
    }

    // online softmax (in-register; cross-half max via permlane)
    float tm = xhalf_max(vmax16(st));
    if (!__all(tm <= mi + DTHR)) {          // T13 defer-rescale
      float mn = fmaxf(mi, tm);
      float scq = hexp2((mi - mn) * CE);
      mi = mn;
      li *= scq;
#pragma unroll
      for (int r = 0; r < 16; ++r) {
        float sc_r = __shfl(scq, (r & 3) + 8 * (r >> 2) + 4 * hi, 64);
        oc0[r] *= sc_r;
        oc1[r] *= sc_r;
      }
    }
    const float nb = mi * CE;
    float rs = 0.f;
#pragma unroll
    for (int r = 0; r < 16; ++r) {
      float p = hexp2(fmaf(st[r], CE, -nb));
      st[r] = p;
      rs += p;
    }
    li += rs;                               // per-half; combined at epilogue

    // pack P into PV A-fragments
    short8 pa[2];
#pragma unroll
    for (int kc = 0; kc < 2; ++kc) {
      const int o = kc * 8;
      unsigned w0 = cvtpk(st[o + 0], st[o + 1]);
      unsigned w1 = cvtpk(st[o + 2], st[o + 3]);
      unsigned w2 = cvtpk(st[o + 4], st[o + 5]);
      unsigned w3 = cvtpk(st[o + 6], st[o + 7]);
      plswap(w0, w2);
      plswap(w1, w3);
      uint4 F;
      F.x = w0; F.y = w1; F.z = w2; F.w = w3;
      pa[kc] = __builtin_bit_cast(short8, F);
    }

    // O += P V over this wave's 32-kv half
    {
      short8 vbf[2][2];
#pragma unroll
      for (int dt = 0; dt < 2; ++dt)
#pragma unroll
        for (int kc = 0; kc < 2; ++kc)
          vbf[dt][kc] = *(const short8*)&vb[(dt * 32 + lq) * 64 +
                          (((wk * 4 + kc * 2 + hi) ^ (lq & 7)) * 8)];
      __builtin_amdgcn_s_setprio(1);
#pragma unroll
      for (int kc = 0; kc < 2; ++kc) {
        oc0 = __builtin_amdgcn_mfma_f32_32x32x16_bf16(pa[kc], vbf[0][kc], oc0, 0, 0, 0);
        oc1 = __builtin_amdgcn_mfma_f32_32x32x16_bf16(pa[kc], vbf[1][kc], oc1, 0, 0, 0);
      }
      __builtin_amdgcn_s_setprio(0);
    }

    if (it + 1 < nit) __syncthreads();
  }

  li = xhalf_add(li);                       // combine the two lane-half partial sums

  // ---- epilogue: merge wk halves, write NORMALIZED bf16 partial + (m, l) ----
  __syncthreads();
  float* obuf = (float*)smem;               // [wq][32 q][64 d] fp32 = 32 KB
  float* mlb  = (float*)&smem[16384];       // [wq][32 q][2] (m, l) = 1 KB
  if (wk == 1) {
#pragma unroll
    for (int r = 0; r < 16; ++r) {
      const int q = (r & 3) + 8 * (r >> 2) + 4 * hi;
      obuf[wq * 2048 + q * 64 + lq]      = oc0[r];
      obuf[wq * 2048 + q * 64 + 32 + lq] = oc1[r];
    }
    if (hi == 0) {
      mlb[wq * 64 + lq * 2 + 0] = mi;
      mlb[wq * 64 + lq * 2 + 1] = li;
    }
  }
  __syncthreads();
  if (wk == 0) {
    unsigned short* dst = sp ? P1 : P0;
    const int hh = bh & 15, bb = bh >> 4;
#pragma unroll
    for (int r = 0; r < 16; ++r) {
      const int q = (r & 3) + 8 * (r >> 2) + 4 * hi;
      float m0 = __shfl(mi, q, 64), l0 = __shfl(li, q, 64);
      float m1 = mlb[wq * 64 + q * 2 + 0], l1 = mlb[wq * 64 + q * 2 + 1];
      float mm = fmaxf(m0, m1);
      float f0 = hexp2((m0 - mm) * CE), f1 = hexp2((m1 - mm) * CE);
      float dn = f0 * l0 + f1 * l1;
      float inv = (dn > 0.f) ? (1.0f / dn) : 0.f;
      float o0 = (f0 * oc0[r] + f1 * obuf[wq * 2048 + q * 64 + lq]) * inv;
      float o1 = (f0 * oc1[r] + f1 * obuf[wq * 2048 + q * 64 + 32 + lq]) * inv;
      int qg = qt * 128 + wq * 32 + q;
      size_t ob = (size_t)(bb * 2048 + qg) * 1024 + hh * 64;
      dst[ob + lq]      = f2bf(o0);
      dst[ob + 32 + lq] = f2bf(o1);
      if (lq == 0) ML[(size_t)(sp * 32 + bh) * 2048 + qg] = make_float2(mm, dn);
    }
  }
#undef STAGE
}

// ---------- combine the two kv-splits: O = (w0*O0 + w1*O1), in place on P0 ----------
__global__ void k_combine(const unsigned short* __restrict__ P1,
                          const float2* __restrict__ ML,
                          unsigned short* __restrict__ P0) {
  const float CE = 0.18033688f;
  int idx = blockIdx.x * 256 + threadIdx.x;
  int flat = idx * 8;
  int c = flat & 1023, t = (flat >> 10) & 2047, b = flat >> 21;
  int bh = b * 16 + (c >> 6);
  float2 a0 = ML[(size_t)bh * 2048 + t];
  float2 a1 = ML[(size_t)(32 + bh) * 2048 + t];
  float mm = fmaxf(a0.x, a1.x);
  float w0 = hexp2((a0.x - mm) * CE) * a0.y;
  float w1 = hexp2((a1.x - mm) * CE) * a1.y;
  float inv = 1.0f / (w0 + w1);
  w0 *= inv; w1 *= inv;
  short8 o0 = *(const short8*)&P0[flat];
  short8 o1 = *(const short8*)&P1[flat];
  short8 o;
#pragma unroll
  for (int k = 0; k < 8; ++k)
    o[k] = (short)f2bf(w0 * bf2f((unsigned short)o0[k]) + w1 * bf2f((unsigned short)o1[k]));
  *(short8*)&P0[flat] = o;
}

// ---------- GEMM2: out = attn_out @ W_proj^T + b (fp32 out) ----------
// 64x128 tile, BK=64 + T2 swizzle (same pattern as GEMM1). Grid (8,64) = 2/CU.
__global__ void k_gemm_proj(const unsigned short* __restrict__ A,
                            const unsigned short* __restrict__ Bt,
                            const float* __restrict__ bias,
                            float* __restrict__ out) {
  __shared__ unsigned short lA[64 * 64];    // 8KB, swizzled
  __shared__ unsigned short lB[128 * 64];   // 16KB, swizzled
  const int K = 1024;
  const int bn = blockIdx.x, bm = blockIdx.y;
  const int tid = threadIdx.x, w = tid >> 6, l = tid & 63;
  const int lr = l & 15, lh = l >> 4;
  const int wm = w >> 1, wn = w & 1;      // 2x2 waves over 64 rows x 128 cols

  f32x4 acc[2][4];
#pragma unroll
  for (int m = 0; m < 2; ++m)
#pragma unroll
    for (int n = 0; n < 4; ++n)
#pragma unroll
      for (int i = 0; i < 4; ++i) acc[m][n][i] = 0.f;

  const int srow = tid >> 3;
  const int scol = ((tid & 7) ^ (srow & 7)) * 8;
  const unsigned short* ga0 = A + (size_t)(bm * 64 + srow) * K + scol;
  const unsigned short* gb0 = Bt + (size_t)(bn * 128 + srow) * K + scol;
  unsigned short* lad = &lA[w * 512];
  unsigned short* lbd = &lB[w * 512];

  for (int kt = 0; kt < K; kt += 64) {
#pragma unroll
    for (int rep = 0; rep < 2; ++rep)
      gl_lds16(ga0 + (size_t)rep * 32 * K + kt, lad + rep * 2048);
#pragma unroll
    for (int rep = 0; rep < 4; ++rep)
      gl_lds16(gb0 + (size_t)rep * 32 * K + kt, lbd + rep * 2048);
    __syncthreads();
#pragma unroll
    for (int ks = 0; ks < 2; ++ks) {
      short8 af[2], bf[4];
#pragma unroll
      for (int m = 0; m < 2; ++m) {
        const int row = wm * 32 + m * 16 + lr;
        af[m] = *(const short8*)&lA[row * 64 + (((ks * 4 + lh) ^ (row & 7)) * 8)];
      }
#pragma unroll
      for (int n = 0; n < 4; ++n) {
        const int row = wn * 64 + n * 16 + lr;
        bf[n] = *(const short8*)&lB[row * 64 + (((ks * 4 + lh) ^ (row & 7)) * 8)];
      }
#pragma unroll
      for (int m = 0; m < 2; ++m)
#pragma unroll
        for (int n = 0; n < 4; ++n)
          acc[m][n] = __builtin_amdgcn_mfma_f32_16x16x32_bf16(af[m], bf[n], acc[m][n], 0, 0, 0);
    }
    __syncthreads();
  }

  const int col0 = bn * 128 + wn * 64;
  const int row0 = bm * 64 + wm * 32;
  float bl[4];
#pragma unroll
  for (int n = 0; n < 4; ++n) bl[n] = bias[col0 + n * 16 + lr];
#pragma unroll
  for (int m = 0; m < 2; ++m)
#pragma unroll
    for (int i = 0; i < 4; ++i) {
      int row = row0 + m * 16 + lh * 4 + i;
#pragma unroll
      for (int n = 0; n < 4; ++n)
        out[(size_t)row * 1024 + col0 + n * 16 + lr] = acc[m][n][i] + bl[n];
    }
}

extern "C" void kernel_launch(void* const* d_in, const int* in_sizes, int n_in,
                              void* d_out, int out_size, void* d_ws, size_t ws_size,
                              hipStream_t stream) {
  const float* x     = (const float*)d_in[0];
  const float* Wattn = (const float*)d_in[1];
  const float* battn = (const float*)d_in[2];
  const float* Wproj = (const float*)d_in[3];
  const float* bproj = (const float*)d_in[4];
  float* out = (float*)d_out;

  char* ws = (char*)d_ws;
  unsigned short* xb  = (unsigned short*)(ws);                  // 8 MB  x bf16 -> sp1 partial
  unsigned short* wat = (unsigned short*)(ws + (8ull  << 20));  // 6 MB  W_attn^T -> ML (1MB)
  unsigned short* wpt = (unsigned short*)(ws + (14ull << 20));  // 2 MB
  unsigned short* qa  = (unsigned short*)(ws + (16ull << 20));  // 8 MB
  unsigned short* ka  = (unsigned short*)(ws + (24ull << 20));  // 8 MB
  unsigned short* va  = (unsigned short*)(ws + (32ull << 20));  // 8 MB  V^T [BH][D][T]
  unsigned short* ob  = (unsigned short*)(ws + (40ull << 20));  // 8 MB  sp0 partial / attn out
  float2* cs          = (float2*)(ws + (48ull << 20));          // 512 KB
  float2* ml          = (float2*)wat;                           // 1 MB (wat dead after GEMM1)

  k_prep<<<6400, 256, 0, stream>>>(x, Wattn, Wproj, xb, wat, wpt, cs);
  k_gemm_qkv<<<dim3(24, 32), 256, 0, stream>>>(xb, wat, battn, cs, qa, ka, va);
  k_attn<<<1024, 512, 0, stream>>>(qa, ka, va, ob, xb, ml);
  k_combine<<<2048, 256, 0, stream>>>(xb, ml, ob);
  k_gemm_proj<<<dim3(8, 64), 256, 0, stream>>>(ob, wpt, bproj, out);
}